// Round 11
// baseline (498.377 us; speedup 1.0000x reference)
//
#include <hip/hip_runtime.h>
#include <cstdint>

// ---------------------------------------------------------------------------
// HCHA (hypergraph conv with attention), f32.
// N=100000 nodes, M=20000 hyperedges, NNZ=1e6, C=128, HEADS=4, FH=32.
// CSR build (single-histogram): bucket_count stores per-block bucket
// histograms + global totals -> bucket_scan (bases) -> cursor_scan
// (per-block cursors via scan over blocks) -> partition2 (ONE pass,
// LDS-cursor scatter, no second histogram).
// sort_node: per-bucket LDS counting sort; emits noff/dinv/neid + RAW alpha
// stream AND rden (per-node alpha sums accumulated in LDS).
// sort_edge: emits eoff/binv/enid + PRE-NORMALIZED alpha (a*rden[n]*binv[e]).
// Aggregations: float4 gathers, 4 quarters x 32 lanes, multi-deep unroll,
// LDS cross-quarter reduce.
// GEMM: A-tile row-major in LDS, W^T pre-transposed, ai head-dot fused.
// Packing: e < 2^15 (M=20000), n < 2^17 (N=1e5).
// ---------------------------------------------------------------------------

#define E_SHIFT 6
#define N_SHIFT 7
#define EB_CAP 4096
#define NB_CAP 2048
#define PCHUNK 4096
#define NBE_CAP 320   // >= ceil(M/64)  = 313
#define NBN_CAP 800   // >= ceil(N/128) = 782

__device__ __forceinline__ unsigned wave_incl_scan(unsigned x) {
#pragma unroll
  for (int s = 1; s < 64; s <<= 1) {
    unsigned t = __shfl_up(x, s, 64);
    if ((int)(threadIdx.x & 63) >= s) x += t;
  }
  return x;
}

// pass A: per-block LDS bucket histogram -> store per-block counts (for the
// cursor scan) + one global atomicAdd per (block,bucket) for totals.
__global__ __launch_bounds__(256) void bucket_count(const int* __restrict__ node_idx,
                                                    const int* __restrict__ edge_idx,
                                                    unsigned* __restrict__ bcnt_e,
                                                    unsigned* __restrict__ bcnt_n,
                                                    unsigned* __restrict__ pcnt_e,
                                                    unsigned* __restrict__ pcnt_n, int nnz) {
  __shared__ unsigned he[NBE_CAP];
  __shared__ unsigned hn[NBN_CAP];
  const int t = threadIdx.x;
  const int base = blockIdx.x * PCHUNK;
  const int cnt = min(PCHUNK, nnz - base);
  for (int b = t; b < NBE_CAP; b += 256) he[b] = 0;
  for (int b = t; b < NBN_CAP; b += 256) hn[b] = 0;
  __syncthreads();
  for (int idx = t; idx < cnt; idx += 256) {
    unsigned e = (unsigned)edge_idx[base + idx];
    unsigned n = (unsigned)node_idx[base + idx];
    atomicAdd(&he[e >> E_SHIFT], 1u);
    atomicAdd(&hn[n >> N_SHIFT], 1u);
  }
  __syncthreads();
  for (int b = t; b < NBE_CAP; b += 256) {
    pcnt_e[(size_t)blockIdx.x * NBE_CAP + b] = he[b];
    if (he[b]) atomicAdd(&bcnt_e[b], he[b]);
  }
  for (int b = t; b < NBN_CAP; b += 256) {
    pcnt_n[(size_t)blockIdx.x * NBN_CAP + b] = hn[b];
    if (hn[b]) atomicAdd(&bcnt_n[b], hn[b]);
  }
}

// single block: exclusive-scan bucket totals -> bucket bases;
// also writes eoff[M]=noff[N]=NNZ.
__global__ __launch_bounds__(1024) void bucket_scan(const unsigned* __restrict__ bcnt_e,
                                                    const unsigned* __restrict__ bcnt_n,
                                                    unsigned* __restrict__ bbase_e,
                                                    unsigned* __restrict__ bbase_n,
                                                    unsigned* __restrict__ eoff,
                                                    unsigned* __restrict__ noff,
                                                    int nbe, int nbn, int M_, int N_, int nnz) {
  __shared__ unsigned wsum[16];
  const int i = threadIdx.x;
  const int lane = i & 63, wid = i >> 6;
  {
    unsigned v = (i < nbe) ? bcnt_e[i] : 0u;
    unsigned incl = wave_incl_scan(v);
    if (lane == 63) wsum[wid] = incl;
    __syncthreads();
    unsigned add = 0;
    for (int w = 0; w < wid; ++w) add += wsum[w];
    unsigned excl = add + incl - v;
    if (i <= nbe) bbase_e[i] = excl;
    __syncthreads();
  }
  {
    unsigned v = (i < nbn) ? bcnt_n[i] : 0u;
    unsigned incl = wave_incl_scan(v);
    if (lane == 63) wsum[wid] = incl;
    __syncthreads();
    unsigned add = 0;
    for (int w = 0; w < wid; ++w) add += wsum[w];
    unsigned excl = add + incl - v;
    if (i <= nbn) bbase_n[i] = excl;
  }
  if (i == 0) { eoff[M_] = (unsigned)nnz; noff[N_] = (unsigned)nnz; }
}

// per-bucket scan over blocks: pcur[b][k] = bbase[k] + prefix_b(pcnt[.][k])
__global__ __launch_bounds__(256) void cursor_scan(const unsigned* __restrict__ pcnt,
                                                   const unsigned* __restrict__ bbase,
                                                   unsigned* __restrict__ pcur,
                                                   int nblocks, int cap) {
  __shared__ unsigned wsum[4];
  const int k = blockIdx.x, t = threadIdx.x;
  const int lane = t & 63, wid = t >> 6;
  unsigned carry = bbase[k];
  for (int b0 = 0; b0 < nblocks; b0 += 256) {
    int b = b0 + t;
    unsigned v = (b < nblocks) ? pcnt[(size_t)b * cap + k] : 0u;
    unsigned incl = wave_incl_scan(v);
    if (lane == 63) wsum[wid] = incl;
    __syncthreads();
    unsigned add = 0;
    for (int w = 0; w < wid; ++w) add += wsum[w];
    if (b < nblocks) pcur[(size_t)b * cap + k] = carry + add + incl - v;
    unsigned tot = wsum[0] + wsum[1] + wsum[2] + wsum[3];
    __syncthreads();
    carry += tot;
  }
}

// pass B: single-pass scatter using precomputed per-block cursors.
__global__ __launch_bounds__(256) void partition2(const int* __restrict__ node_idx,
                                                  const int* __restrict__ edge_idx,
                                                  const unsigned* __restrict__ pcur_e,
                                                  const unsigned* __restrict__ pcur_n,
                                                  unsigned* __restrict__ tmp_e,
                                                  unsigned* __restrict__ tmp_n, int nnz) {
  __shared__ unsigned he[NBE_CAP];
  __shared__ unsigned hn[NBN_CAP];
  const int t = threadIdx.x;
  const int base = blockIdx.x * PCHUNK;
  const int cnt = min(PCHUNK, nnz - base);

  for (int b = t; b < NBE_CAP; b += 256) he[b] = pcur_e[(size_t)blockIdx.x * NBE_CAP + b];
  for (int b = t; b < NBN_CAP; b += 256) hn[b] = pcur_n[(size_t)blockIdx.x * NBN_CAP + b];
  __syncthreads();

  for (int idx = t; idx < cnt; idx += 256) {
    unsigned e = (unsigned)edge_idx[base + idx];
    unsigned n = (unsigned)node_idx[base + idx];
    unsigned pe = atomicAdd(&he[e >> E_SHIFT], 1u);
    tmp_e[pe] = ((e & 63u) << 17) | n;
    unsigned pn = atomicAdd(&hn[n >> N_SHIFT], 1u);
    tmp_n[pn] = ((n & 127u) << 15) | e;
  }
}

__device__ __forceinline__ float4 alpha4(const float* __restrict__ ai,
                                         const float* __restrict__ aj,
                                         unsigned n, unsigned e) {
  float4 av = *(const float4*)&ai[(size_t)n * 4];
  float4 bv = *(const float4*)&aj[(size_t)e * 4];
  float v0 = av.x + bv.x, v1 = av.y + bv.y, v2 = av.z + bv.z, v3 = av.w + bv.w;
  v0 = v0 > 0.f ? v0 : 0.2f * v0;
  v1 = v1 > 0.f ? v1 : 0.2f * v1;
  v2 = v2 > 0.f ? v2 : 0.2f * v2;
  v3 = v3 > 0.f ? v3 : 0.2f * v3;
  return make_float4(expf(v0), expf(v1), expf(v2), expf(v3));
}

// pass C (nodes): per-bucket LDS counting sort. Emits noff/dinv, node-ordered
// edge ids + RAW alpha stream, and rden (LDS-accumulated alpha sums).
__global__ __launch_bounds__(256) void sort_node_exp(const unsigned* __restrict__ tmp,
                                                     const unsigned* __restrict__ bbase,
                                                     int N_,
                                                     const float* __restrict__ ai,
                                                     const float* __restrict__ aj,
                                                     float* __restrict__ ealpha_n,
                                                     int* __restrict__ neid,
                                                     unsigned* __restrict__ noff,
                                                     float* __restrict__ dinv,
                                                     float* __restrict__ rden) {
  __shared__ unsigned cur[128];
  __shared__ unsigned sbuf[NB_CAP];
  __shared__ __align__(16) float dsum[128][4];
  __shared__ unsigned wtot;
  int b = blockIdx.x, t = threadIdx.x;
  int n0 = b << N_SHIFT;
  unsigned base = bbase[b];
  int cnt = (int)(bbase[b + 1] - base);
  if (t < 128) cur[t] = 0;
  for (int i = t; i < 512; i += 256) ((float*)dsum)[i] = 0.f;
  __syncthreads();
  for (int idx = t; idx < cnt; idx += 256) {
    unsigned key = tmp[base + idx] >> 15;
    atomicAdd(&cur[key], 1u);
  }
  __syncthreads();
  {  // exclusive scan of 128 counts across waves 0..1
    unsigned c = (t < 128) ? cur[t] : 0u;
    unsigned incl = wave_incl_scan(c);
    if (t == 63) wtot = incl;
    __syncthreads();
    unsigned excl = incl - c + ((t >= 64 && t < 128) ? wtot : 0u);
    if (t < 128) {
      int n = n0 + t;
      if (n < N_) {
        noff[n] = base + excl;
        dinv[n] = c ? 1.f / (float)c : 0.f;
      }
      cur[t] = excl;
    }
  }
  __syncthreads();
  for (int idx = t; idx < cnt; idx += 256) {
    unsigned p = tmp[base + idx];
    unsigned key = p >> 15;
    unsigned pos = atomicAdd(&cur[key], 1u);
    if (pos < NB_CAP) {
      sbuf[pos] = p;
    } else {  // overflow fallback (statistically never): pos is final slot
      unsigned e = p & 0x7FFFu;
      float4 al = alpha4(ai, aj, n0 + key, e);
      atomicAdd(&dsum[key][0], al.x); atomicAdd(&dsum[key][1], al.y);
      atomicAdd(&dsum[key][2], al.z); atomicAdd(&dsum[key][3], al.w);
      *(float4*)&ealpha_n[(size_t)(base + pos) * 4] = al;
      neid[base + pos] = (int)e;
    }
  }
  __syncthreads();
  int lim = min(cnt, NB_CAP);
  for (int idx = t; idx < lim; idx += 256) {
    unsigned p = sbuf[idx];
    unsigned nl = p >> 15, e = p & 0x7FFFu;
    float4 al = alpha4(ai, aj, n0 + nl, e);
    atomicAdd(&dsum[nl][0], al.x); atomicAdd(&dsum[nl][1], al.y);
    atomicAdd(&dsum[nl][2], al.z); atomicAdd(&dsum[nl][3], al.w);
    *(float4*)&ealpha_n[(size_t)(base + idx) * 4] = al;
    neid[base + idx] = (int)e;
  }
  __syncthreads();
  if (t < 128) {
    int n = n0 + t;
    if (n < N_) {
      *(float4*)&rden[(size_t)n * 4] =
          make_float4(1.f / (dsum[t][0] + 1e-16f), 1.f / (dsum[t][1] + 1e-16f),
                      1.f / (dsum[t][2] + 1e-16f), 1.f / (dsum[t][3] + 1e-16f));
    }
  }
}

// pass C (edges): per-bucket LDS counting sort; emits eoff/binv + coalesced
// edge-ordered node ids + PRE-NORMALIZED alpha (ealpha * rden[n] * binv[e]).
__global__ __launch_bounds__(256) void sort_edge_exp(const unsigned* __restrict__ tmp,
                                                     const unsigned* __restrict__ bbase,
                                                     int M_,
                                                     const float* __restrict__ ai,
                                                     const float* __restrict__ aj,
                                                     const float* __restrict__ rden,
                                                     float* __restrict__ alpha_e,
                                                     int* __restrict__ enid,
                                                     unsigned* __restrict__ eoff,
                                                     float* __restrict__ binv) {
  __shared__ unsigned cur[64];
  __shared__ float binv_s[64];
  __shared__ unsigned sbuf[EB_CAP];
  int b = blockIdx.x, t = threadIdx.x;
  int e0 = b << E_SHIFT;
  unsigned base = bbase[b];
  int cnt = (int)(bbase[b + 1] - base);
  if (t < 64) cur[t] = 0;
  __syncthreads();
  for (int idx = t; idx < cnt; idx += 256) {
    unsigned key = tmp[base + idx] >> 17;
    atomicAdd(&cur[key], 1u);
  }
  __syncthreads();
  {  // local exclusive scan of 64 counts (wave 0 relevant)
    unsigned c = (t < 64) ? cur[t] : 0u;
    unsigned incl = wave_incl_scan(c);
    unsigned excl = incl - c;
    if (t < 64) {
      float bv = c ? 1.f / (float)c : 0.f;
      binv_s[t] = bv;
      int e = e0 + t;
      if (e < M_) {
        eoff[e] = base + excl;
        binv[e] = bv;
      }
      cur[t] = excl;  // becomes the placement cursor
    }
  }
  __syncthreads();
  for (int idx = t; idx < cnt; idx += 256) {
    unsigned p = tmp[base + idx];
    unsigned key = p >> 17;
    unsigned pos = atomicAdd(&cur[key], 1u);
    if (pos < EB_CAP) {
      sbuf[pos] = p;
    } else {  // overflow fallback (statistically never): pos is final slot
      unsigned n = p & 0x1FFFFu;
      float4 al = alpha4(ai, aj, n, e0 + key);
      float4 rd = *(const float4*)&rden[(size_t)n * 4];
      float bv = binv_s[key];
      *(float4*)&alpha_e[(size_t)(base + pos) * 4] =
          make_float4(al.x * rd.x * bv, al.y * rd.y * bv, al.z * rd.z * bv, al.w * rd.w * bv);
      enid[base + pos] = (int)n;
    }
  }
  __syncthreads();
  int lim = min(cnt, EB_CAP);
  for (int idx = t; idx < lim; idx += 256) {
    unsigned p = sbuf[idx];
    unsigned key = p >> 17, n = p & 0x1FFFFu;
    float4 al = alpha4(ai, aj, n, e0 + key);
    float4 rd = *(const float4*)&rden[(size_t)n * 4];
    float bv = binv_s[key];
    *(float4*)&alpha_e[(size_t)(base + idx) * 4] =
        make_float4(al.x * rd.x * bv, al.y * rd.y * bv, al.z * rd.z * bv, al.w * rd.w * bv);
    enid[base + idx] = (int)n;
  }
}

// WT[k*128+o] = W[o*128+k]   (one-time 64KB transpose)
__global__ __launch_bounds__(256) void wtrans(const float* __restrict__ W,
                                              float* __restrict__ WT) {
  int idx = blockIdx.x * 256 + threadIdx.x;
  if (idx >= 128 * 128) return;
  int k = idx >> 7, o = idx & 127;
  WT[idx] = W[o * 128 + k];
}

// C[r,o] = sum_k A[r,k] * WT[k,o]; A rows x 128, WT 128x128 (pre-transposed).
// A-tile row-major in LDS: staging coalesced & conflict-free; reads broadcast.
// Optional fused head-dot epilogue: aiout[r,h] = sum_f C[r,h*32+f]*att[h*64+f].
#define GM 64
__global__ __launch_bounds__(256) void gemm128t(const float* __restrict__ A,
                                                const float* __restrict__ WT,
                                                float* __restrict__ C, int rows,
                                                const float* __restrict__ att,
                                                float* __restrict__ aiout) {
  __shared__ __align__(16) float Ast[GM][132];  // row-major, pad 132
  const int tid = threadIdx.x;
  const int row0 = blockIdx.x * GM;

  for (int idx = tid; idx < GM * 32; idx += 256) {  // float4-granular staging
    int r = idx >> 5, kq = idx & 31;
    int gr = row0 + r;
    float4 v = (gr < rows) ? *(const float4*)&A[(size_t)gr * 128 + kq * 4]
                           : make_float4(0.f, 0.f, 0.f, 0.f);
    *(float4*)&Ast[r][kq * 4] = v;
  }
  __syncthreads();

  const int tr = tid >> 5, tc = tid & 31;
  const int r0 = tr * 8, c0 = tc * 4;
  float acc[8][4] = {{0.f}};

  for (int k = 0; k < 128; k += 4) {
    float4 b0 = *(const float4*)&WT[(k + 0) * 128 + c0];
    float4 b1 = *(const float4*)&WT[(k + 1) * 128 + c0];
    float4 b2 = *(const float4*)&WT[(k + 2) * 128 + c0];
    float4 b3 = *(const float4*)&WT[(k + 3) * 128 + c0];
#pragma unroll
    for (int i = 0; i < 8; ++i) {
      float4 a = *(const float4*)&Ast[r0 + i][k];  // broadcast read
      acc[i][0] += a.x * b0.x; acc[i][1] += a.x * b0.y; acc[i][2] += a.x * b0.z; acc[i][3] += a.x * b0.w;
      acc[i][0] += a.y * b1.x; acc[i][1] += a.y * b1.y; acc[i][2] += a.y * b1.z; acc[i][3] += a.y * b1.w;
      acc[i][0] += a.z * b2.x; acc[i][1] += a.z * b2.y; acc[i][2] += a.z * b2.z; acc[i][3] += a.z * b2.w;
      acc[i][0] += a.w * b3.x; acc[i][1] += a.w * b3.y; acc[i][2] += a.w * b3.z; acc[i][3] += a.w * b3.w;
    }
  }

#pragma unroll
  for (int i = 0; i < 8; ++i) {
    int gr = row0 + r0 + i;
    if (gr < rows)
      *(float4*)&C[(size_t)gr * 128 + c0] = make_float4(acc[i][0], acc[i][1], acc[i][2], acc[i][3]);
  }

  if (att) {  // fused ai head-dot: cols c0..c0+3 all in head h = tc>>3
    int h = tc >> 3;
    float4 w = *(const float4*)&att[h * 64 + (c0 & 31)];
#pragma unroll
    for (int i = 0; i < 8; ++i) {
      float p = acc[i][0] * w.x + acc[i][1] * w.y + acc[i][2] * w.z + acc[i][3] * w.w;
      p += __shfl_xor(p, 1);
      p += __shfl_xor(p, 2);
      p += __shfl_xor(p, 4);
      if ((tc & 7) == 0) {
        int gr = row0 + r0 + i;
        if (gr < rows) aiout[(size_t)gr * 4 + h] = p;
      }
    }
  }
}

// u[h,k] = sum_f att1[h*64+32+f] * W_he[(h*32+f)*128 + k]
__global__ __launch_bounds__(256) void make_u(const float* __restrict__ W_he,
                                              const float* __restrict__ att1,
                                              float* __restrict__ u) {
  int idx = blockIdx.x * 256 + threadIdx.x;
  if (idx >= 512) return;
  int h = idx >> 7, k = idx & 127;
  float s = 0.f;
#pragma unroll
  for (int f = 0; f < 32; ++f)
    s += att1[h * 64 + 32 + f] * W_he[(size_t)(h * 32 + f) * 128 + k];
  u[h * 128 + k] = s;
}

// aj[e,h] = hea[e,:] . u[h,:]
__global__ __launch_bounds__(256) void att_dot_full(const float* __restrict__ feat,
                                                    const float* __restrict__ u,
                                                    float* __restrict__ outv, int rows) {
  int idx = blockIdx.x * 256 + threadIdx.x;
  if (idx >= rows * 4) return;
  int v = idx >> 2, h = idx & 3;
  const float4* fp = (const float4*)(feat + (size_t)v * 128);
  const float4* up = (const float4*)(u + h * 128);
  float s = 0.f;
#pragma unroll
  for (int q = 0; q < 32; ++q) {
    float4 a = up[q], f = fp[q];
    s += a.x * f.x + a.y * f.y + a.z * f.z + a.w * f.w;
  }
  outv[idx] = s;
}

// out_e[e,:] = sum_i alpha_pre[i,h] * x1[node_i,:]   (alpha pre-normalized)
// 4 quarters x 32 lanes; lane loads float4 (full 512B row per quarter).
__global__ __launch_bounds__(128) void edge_aggregate1(const float* __restrict__ x1,
                                                       const float* __restrict__ alpha_e,
                                                       const int* __restrict__ enid,
                                                       const unsigned* __restrict__ eoff,
                                                       float* __restrict__ out_e) {
  __shared__ float red[4][128];
  const int e = blockIdx.x, t = threadIdx.x;
  const int q = t >> 5, l = t & 31, hh = l >> 3;
  const unsigned s = eoff[e], en = eoff[e + 1];
  float4 A0 = make_float4(0.f, 0.f, 0.f, 0.f), A1 = A0, A2 = A0, A3 = A0;
  unsigned j = s + q;
  for (; j + 12 < en; j += 16) {
    int n0 = enid[j], n1 = enid[j + 4], n2 = enid[j + 8], n3 = enid[j + 12];
    float w0 = alpha_e[(size_t)j * 4 + hh];
    float w1 = alpha_e[(size_t)(j + 4) * 4 + hh];
    float w2 = alpha_e[(size_t)(j + 8) * 4 + hh];
    float w3 = alpha_e[(size_t)(j + 12) * 4 + hh];
    float4 a0 = *(const float4*)&x1[(size_t)n0 * 128 + l * 4];
    float4 a1 = *(const float4*)&x1[(size_t)n1 * 128 + l * 4];
    float4 a2 = *(const float4*)&x1[(size_t)n2 * 128 + l * 4];
    float4 a3 = *(const float4*)&x1[(size_t)n3 * 128 + l * 4];
    A0.x += w0 * a0.x; A0.y += w0 * a0.y; A0.z += w0 * a0.z; A0.w += w0 * a0.w;
    A1.x += w1 * a1.x; A1.y += w1 * a1.y; A1.z += w1 * a1.z; A1.w += w1 * a1.w;
    A2.x += w2 * a2.x; A2.y += w2 * a2.y; A2.z += w2 * a2.z; A2.w += w2 * a2.w;
    A3.x += w3 * a3.x; A3.y += w3 * a3.y; A3.z += w3 * a3.z; A3.w += w3 * a3.w;
  }
  for (; j < en; j += 4) {
    int n = enid[j];
    float w = alpha_e[(size_t)j * 4 + hh];
    float4 a = *(const float4*)&x1[(size_t)n * 128 + l * 4];
    A0.x += w * a.x; A0.y += w * a.y; A0.z += w * a.z; A0.w += w * a.w;
  }
  float4 A = make_float4((A0.x + A1.x) + (A2.x + A3.x), (A0.y + A1.y) + (A2.y + A3.y),
                         (A0.z + A1.z) + (A2.z + A3.z), (A0.w + A1.w) + (A2.w + A3.w));
  *(float4*)&red[q][l * 4] = A;
  __syncthreads();
  out_e[(size_t)e * 128 + t] = red[0][t] + red[1][t] + red[2][t] + red[3][t];
}

// h[v,:] = elu(Dinv[v]*rden[v,h] * sum_j ealpha_n[j,h]*out_e[neid[j],:] + bias1)
__global__ __launch_bounds__(128) void node_aggregate1(const float* __restrict__ out_e,
                                                       const float* __restrict__ ealpha_n,
                                                       const float* __restrict__ rden,
                                                       const float* __restrict__ dinv,
                                                       const float* __restrict__ bias1,
                                                       const int* __restrict__ neid,
                                                       const unsigned* __restrict__ noff,
                                                       float* __restrict__ hout) {
  __shared__ float red[4][128];
  const int v = blockIdx.x, t = threadIdx.x;
  const int q = t >> 5, l = t & 31, hh = l >> 3;
  const unsigned s = noff[v], en = noff[v + 1];
  float4 A0 = make_float4(0.f, 0.f, 0.f, 0.f), A1 = A0;
  unsigned j = s + q;
  for (; j + 4 < en; j += 8) {
    int e0 = neid[j], e1 = neid[j + 4];
    float w0 = ealpha_n[(size_t)j * 4 + hh];
    float w1 = ealpha_n[(size_t)(j + 4) * 4 + hh];
    float4 a0 = *(const float4*)&out_e[(size_t)e0 * 128 + l * 4];
    float4 a1 = *(const float4*)&out_e[(size_t)e1 * 128 + l * 4];
    A0.x += w0 * a0.x; A0.y += w0 * a0.y; A0.z += w0 * a0.z; A0.w += w0 * a0.w;
    A1.x += w1 * a1.x; A1.y += w1 * a1.y; A1.z += w1 * a1.z; A1.w += w1 * a1.w;
  }
  for (; j < en; j += 4) {
    int e0 = neid[j];
    float w = ealpha_n[(size_t)j * 4 + hh];
    float4 a = *(const float4*)&out_e[(size_t)e0 * 128 + l * 4];
    A0.x += w * a.x; A0.y += w * a.y; A0.z += w * a.z; A0.w += w * a.w;
  }
  float4 A = make_float4(A0.x + A1.x, A0.y + A1.y, A0.z + A1.z, A0.w + A1.w);
  *(float4*)&red[q][l * 4] = A;
  __syncthreads();
  float rd = dinv[v] * rden[(size_t)v * 4 + (t >> 5)];
  float val = rd * (red[0][t] + red[1][t] + red[2][t] + red[3][t]) + bias1[t];
  hout[(size_t)v * 128 + t] = val > 0.f ? val : expm1f(val);
}

// oe[e,:] = Binv[e] * sum_i h[node_i,:]
__global__ __launch_bounds__(128) void edge_aggregate2(const float* __restrict__ hfeat,
                                                       const float* __restrict__ binv,
                                                       const int* __restrict__ enid,
                                                       const unsigned* __restrict__ eoff,
                                                       float* __restrict__ oe) {
  __shared__ float red[4][128];
  const int e = blockIdx.x, t = threadIdx.x;
  const int q = t >> 5, l = t & 31;
  const unsigned s = eoff[e], en = eoff[e + 1];
  float4 A0 = make_float4(0.f, 0.f, 0.f, 0.f), A1 = A0, A2 = A0, A3 = A0;
  unsigned j = s + q;
  for (; j + 12 < en; j += 16) {
    int n0 = enid[j], n1 = enid[j + 4], n2 = enid[j + 8], n3 = enid[j + 12];
    float4 a0 = *(const float4*)&hfeat[(size_t)n0 * 128 + l * 4];
    float4 a1 = *(const float4*)&hfeat[(size_t)n1 * 128 + l * 4];
    float4 a2 = *(const float4*)&hfeat[(size_t)n2 * 128 + l * 4];
    float4 a3 = *(const float4*)&hfeat[(size_t)n3 * 128 + l * 4];
    A0.x += a0.x; A0.y += a0.y; A0.z += a0.z; A0.w += a0.w;
    A1.x += a1.x; A1.y += a1.y; A1.z += a1.z; A1.w += a1.w;
    A2.x += a2.x; A2.y += a2.y; A2.z += a2.z; A2.w += a2.w;
    A3.x += a3.x; A3.y += a3.y; A3.z += a3.z; A3.w += a3.w;
  }
  for (; j < en; j += 4) {
    int n = enid[j];
    float4 a = *(const float4*)&hfeat[(size_t)n * 128 + l * 4];
    A0.x += a.x; A0.y += a.y; A0.z += a.z; A0.w += a.w;
  }
  float4 A = make_float4((A0.x + A1.x) + (A2.x + A3.x), (A0.y + A1.y) + (A2.y + A3.y),
                         (A0.z + A1.z) + (A2.z + A3.z), (A0.w + A1.w) + (A2.w + A3.w));
  *(float4*)&red[q][l * 4] = A;
  __syncthreads();
  oe[(size_t)e * 128 + t] = binv[e] * (red[0][t] + red[1][t] + red[2][t] + red[3][t]);
}

// out[v,:] = Dinv[v] * sum_j oe2[neid[j],:] + bias2
__global__ __launch_bounds__(128) void node_aggregate2(const float* __restrict__ oe2,
                                                       const float* __restrict__ dinv,
                                                       const float* __restrict__ bias2,
                                                       const int* __restrict__ neid,
                                                       const unsigned* __restrict__ noff,
                                                       float* __restrict__ out) {
  __shared__ float red[4][128];
  const int v = blockIdx.x, t = threadIdx.x;
  const int q = t >> 5, l = t & 31;
  const unsigned s = noff[v], en = noff[v + 1];
  float4 A0 = make_float4(0.f, 0.f, 0.f, 0.f), A1 = A0;
  unsigned j = s + q;
  for (; j + 4 < en; j += 8) {
    int e0 = neid[j], e1 = neid[j + 4];
    float4 a0 = *(const float4*)&oe2[(size_t)e0 * 128 + l * 4];
    float4 a1 = *(const float4*)&oe2[(size_t)e1 * 128 + l * 4];
    A0.x += a0.x; A0.y += a0.y; A0.z += a0.z; A0.w += a0.w;
    A1.x += a1.x; A1.y += a1.y; A1.z += a1.z; A1.w += a1.w;
  }
  for (; j < en; j += 4) {
    int e0 = neid[j];
    float4 a = *(const float4*)&oe2[(size_t)e0 * 128 + l * 4];
    A0.x += a.x; A0.y += a.y; A0.z += a.z; A0.w += a.w;
  }
  float4 A = make_float4(A0.x + A1.x, A0.y + A1.y, A0.z + A1.z, A0.w + A1.w);
  *(float4*)&red[q][l * 4] = A;
  __syncthreads();
  out[(size_t)v * 128 + t] = dinv[v] * (red[0][t] + red[1][t] + red[2][t] + red[3][t]) + bias2[t];
}

extern "C" void kernel_launch(void* const* d_in, const int* in_sizes, int n_in,
                              void* d_out, int out_size, void* d_ws, size_t ws_size,
                              hipStream_t stream) {
  (void)n_in; (void)out_size; (void)ws_size;
  const float* x      = (const float*)d_in[0];
  const float* hea    = (const float*)d_in[1];
  const float* lin1W  = (const float*)d_in[2];
  const float* helinW = (const float*)d_in[3];
  const float* att1   = (const float*)d_in[4];
  const float* bias1  = (const float*)d_in[5];
  const float* lin2W  = (const float*)d_in[6];
  const float* bias2  = (const float*)d_in[7];
  const int* node_idx = (const int*)d_in[8];
  const int* edge_idx = (const int*)d_in[9];
  float* out = (float*)d_out;

  const int N   = in_sizes[0] / 128;
  const int M   = in_sizes[1] / 128;
  const int NNZ = in_sizes[8];
  const int NBE = (M + 63) >> E_SHIFT;
  const int NBN = (N + 127) >> N_SHIFT;
  const int g_pchunk = (NNZ + PCHUNK - 1) / PCHUNK;

  char* base = (char*)d_ws;
  size_t off = 0;
  auto alloc = [&](size_t bytes) -> char* {
    char* p = base + off;
    off = (off + bytes + 255) & ~(size_t)255;
    return p;
  };
  float* x1    = (float*)alloc((size_t)N * 128 * 4);  // x1; later oe2 (M rows)
  float* hbuf  = (float*)alloc((size_t)N * 128 * 4);  // h
  float* heoe  = (float*)alloc((size_t)M * 128 * 4);  // out_e -> oe_pre
  float* ai    = (float*)alloc((size_t)N * 4 * 4);
  float* aj    = (float*)alloc((size_t)M * 4 * 4);
  float* u     = (float*)alloc(512 * 4);
  float* WT1   = (float*)alloc(128 * 128 * 4);
  float* WT2   = (float*)alloc(128 * 128 * 4);
  float* dinv  = (float*)alloc((size_t)N * 4);
  float* binv  = (float*)alloc((size_t)M * 4);
  float* rden  = (float*)alloc((size_t)N * 4 * 4);
  char* zstart = base + off;                           // ---- zeroed region ----
  unsigned* bcnt_e = (unsigned*)alloc((size_t)NBE * 4);
  unsigned* bcnt_n = (unsigned*)alloc((size_t)NBN * 4);
  size_t zbytes = (size_t)((base + off) - zstart);     // ---- end zero region ----
  float* alpha_e  = (float*)alloc((size_t)NNZ * 4 * 4);
  float* ealpha_n = (float*)alloc((size_t)NNZ * 4 * 4);
  unsigned* tmp_e = (unsigned*)alloc((size_t)NNZ * 4);
  unsigned* tmp_n = (unsigned*)alloc((size_t)NNZ * 4);
  unsigned* noff  = (unsigned*)alloc((size_t)(N + 1) * 4);
  unsigned* eoff  = (unsigned*)alloc((size_t)(M + 1) * 4);
  unsigned* bbase_e = (unsigned*)alloc((size_t)(NBE + 1) * 4);
  unsigned* bbase_n = (unsigned*)alloc((size_t)(NBN + 1) * 4);
  unsigned* pcnt_e = (unsigned*)alloc((size_t)g_pchunk * NBE_CAP * 4);
  unsigned* pcnt_n = (unsigned*)alloc((size_t)g_pchunk * NBN_CAP * 4);
  unsigned* pcur_e = (unsigned*)alloc((size_t)g_pchunk * NBE_CAP * 4);
  unsigned* pcur_n = (unsigned*)alloc((size_t)g_pchunk * NBN_CAP * 4);
  int* enid       = (int*)alloc((size_t)NNZ * 4);
  int* neid       = (int*)alloc((size_t)NNZ * 4);

  hipMemsetAsync(zstart, 0, zbytes, stream);

  bucket_count<<<g_pchunk, 256, 0, stream>>>(node_idx, edge_idx, bcnt_e, bcnt_n,
                                             pcnt_e, pcnt_n, NNZ);
  bucket_scan<<<1, 1024, 0, stream>>>(bcnt_e, bcnt_n, bbase_e, bbase_n,
                                      eoff, noff, NBE, NBN, M, N, NNZ);
  cursor_scan<<<NBE, 256, 0, stream>>>(pcnt_e, bbase_e, pcur_e, g_pchunk, NBE_CAP);
  cursor_scan<<<NBN, 256, 0, stream>>>(pcnt_n, bbase_n, pcur_n, g_pchunk, NBN_CAP);
  partition2<<<g_pchunk, 256, 0, stream>>>(node_idx, edge_idx, pcur_e, pcur_n,
                                           tmp_e, tmp_n, NNZ);

  wtrans<<<64, 256, 0, stream>>>(lin1W, WT1);
  wtrans<<<64, 256, 0, stream>>>(lin2W, WT2);
  gemm128t<<<(N + GM - 1) / GM, 256, 0, stream>>>(x, WT1, x1, N, att1, ai);
  make_u<<<2, 256, 0, stream>>>(helinW, att1, u);
  att_dot_full<<<(M * 4 + 255) / 256, 256, 0, stream>>>(hea, u, aj, M);

  sort_node_exp<<<NBN, 256, 0, stream>>>(tmp_n, bbase_n, N, ai, aj, ealpha_n, neid,
                                         noff, dinv, rden);
  sort_edge_exp<<<NBE, 256, 0, stream>>>(tmp_e, bbase_e, M, ai, aj, rden, alpha_e, enid,
                                         eoff, binv);

  edge_aggregate1<<<M, 128, 0, stream>>>(x1, alpha_e, enid, eoff, heoe);
  node_aggregate1<<<N, 128, 0, stream>>>(heoe, ealpha_n, rden, dinv, bias1, neid, noff, hbuf);

  edge_aggregate2<<<M, 128, 0, stream>>>(hbuf, binv, enid, eoff, heoe);
  gemm128t<<<(M + GM - 1) / GM, 256, 0, stream>>>(heoe, WT2, x1, M, nullptr, nullptr);
  node_aggregate2<<<N, 128, 0, stream>>>(x1, dinv, bias2, neid, noff, out);
}

// Round 12
// 488.696 us; speedup vs baseline: 1.0198x; 1.0198x over previous
//
#include <hip/hip_runtime.h>
#include <cstdint>

// ---------------------------------------------------------------------------
// HCHA (hypergraph conv with attention), f32.
// N=100000 nodes, M=20000 hyperedges, NNZ=1e6, C=128, HEADS=4, FH=32.
// CSR build (round-9 structure, fastest measured): bucket_count -> 1-block
// bucket_scan -> block-local multi-split partition (2nd histogram + reserve
// atomics) -> per-bucket LDS counting sorts.
// sort_node: emits noff/dinv/neid + RAW alpha stream AND rden (per-node
// alpha sums accumulated in LDS) -- node_denom pass deleted.
// sort_edge: emits eoff/binv/enid + PRE-NORMALIZED alpha (a*rden[n]*binv[e]).
// Aggregations: float4 gathers, 4 quarters x 32 lanes, multi-deep unroll,
// LDS cross-quarter reduce. Measured pinned at ~3.4-3.5 TB/s L2-fill
// (random-gather roofline for this graph).
// GEMM: A-tile row-major in LDS, W^T pre-transposed, ai head-dot fused.
// Packing: e < 2^15 (M=20000), n < 2^17 (N=1e5).
// ---------------------------------------------------------------------------

#define E_SHIFT 6
#define N_SHIFT 7
#define EB_CAP 4096
#define NB_CAP 2048
#define PCHUNK 4096
#define NBE_CAP 320   // >= ceil(M/64)  = 313
#define NBN_CAP 800   // >= ceil(N/128) = 782

__device__ __forceinline__ unsigned wave_incl_scan(unsigned x) {
#pragma unroll
  for (int s = 1; s < 64; s <<= 1) {
    unsigned t = __shfl_up(x, s, 64);
    if ((int)(threadIdx.x & 63) >= s) x += t;
  }
  return x;
}

// pass A: per-block LDS bucket histogram -> one global atomicAdd per
// (block,bucket). No per-id atomics.
__global__ __launch_bounds__(256) void bucket_count(const int* __restrict__ node_idx,
                                                    const int* __restrict__ edge_idx,
                                                    unsigned* __restrict__ bcnt_e,
                                                    unsigned* __restrict__ bcnt_n, int nnz) {
  __shared__ unsigned he[NBE_CAP];
  __shared__ unsigned hn[NBN_CAP];
  const int t = threadIdx.x;
  const int base = blockIdx.x * PCHUNK;
  const int cnt = min(PCHUNK, nnz - base);
  for (int b = t; b < NBE_CAP; b += 256) he[b] = 0;
  for (int b = t; b < NBN_CAP; b += 256) hn[b] = 0;
  __syncthreads();
  for (int idx = t; idx < cnt; idx += 256) {
    unsigned e = (unsigned)edge_idx[base + idx];
    unsigned n = (unsigned)node_idx[base + idx];
    atomicAdd(&he[e >> E_SHIFT], 1u);
    atomicAdd(&hn[n >> N_SHIFT], 1u);
  }
  __syncthreads();
  for (int b = t; b < NBE_CAP; b += 256) if (he[b]) atomicAdd(&bcnt_e[b], he[b]);
  for (int b = t; b < NBN_CAP; b += 256) if (hn[b]) atomicAdd(&bcnt_n[b], hn[b]);
}

// single block: exclusive-scan bucket totals -> bucket bases + cursors;
// also writes eoff[M]=noff[N]=NNZ.
__global__ __launch_bounds__(1024) void bucket_scan(const unsigned* __restrict__ bcnt_e,
                                                    const unsigned* __restrict__ bcnt_n,
                                                    unsigned* __restrict__ bbase_e,
                                                    unsigned* __restrict__ bcur_e,
                                                    unsigned* __restrict__ bbase_n,
                                                    unsigned* __restrict__ bcur_n,
                                                    unsigned* __restrict__ eoff,
                                                    unsigned* __restrict__ noff,
                                                    int nbe, int nbn, int M_, int N_, int nnz) {
  __shared__ unsigned wsum[16];
  const int i = threadIdx.x;
  const int lane = i & 63, wid = i >> 6;
  {
    unsigned v = (i < nbe) ? bcnt_e[i] : 0u;
    unsigned incl = wave_incl_scan(v);
    if (lane == 63) wsum[wid] = incl;
    __syncthreads();
    unsigned add = 0;
    for (int w = 0; w < wid; ++w) add += wsum[w];
    unsigned excl = add + incl - v;
    if (i <= nbe) bbase_e[i] = excl;
    if (i < nbe) bcur_e[i] = excl;
    __syncthreads();
  }
  {
    unsigned v = (i < nbn) ? bcnt_n[i] : 0u;
    unsigned incl = wave_incl_scan(v);
    if (lane == 63) wsum[wid] = incl;
    __syncthreads();
    unsigned add = 0;
    for (int w = 0; w < wid; ++w) add += wsum[w];
    unsigned excl = add + incl - v;
    if (i <= nbn) bbase_n[i] = excl;
    if (i < nbn) bcur_n[i] = excl;
  }
  if (i == 0) { eoff[M_] = (unsigned)nnz; noff[N_] = (unsigned)nnz; }
}

// pass B: block-local multi-split. LDS histogram -> one global atomic per
// (block,bucket) to reserve ranges -> LDS-cursor scatter of u32 payloads.
__global__ __launch_bounds__(256) void partition2(const int* __restrict__ node_idx,
                                                  const int* __restrict__ edge_idx,
                                                  unsigned* __restrict__ bcur_e,
                                                  unsigned* __restrict__ bcur_n,
                                                  unsigned* __restrict__ tmp_e,
                                                  unsigned* __restrict__ tmp_n, int nnz) {
  __shared__ unsigned he[NBE_CAP];
  __shared__ unsigned hn[NBN_CAP];
  const int t = threadIdx.x;
  const int base = blockIdx.x * PCHUNK;
  const int cnt = min(PCHUNK, nnz - base);

  for (int b = t; b < NBE_CAP; b += 256) he[b] = 0;
  for (int b = t; b < NBN_CAP; b += 256) hn[b] = 0;
  __syncthreads();

  for (int idx = t; idx < cnt; idx += 256) {
    unsigned e = (unsigned)edge_idx[base + idx];
    unsigned n = (unsigned)node_idx[base + idx];
    atomicAdd(&he[e >> E_SHIFT], 1u);
    atomicAdd(&hn[n >> N_SHIFT], 1u);
  }
  __syncthreads();

  for (int b = t; b < NBE_CAP; b += 256) {
    unsigned c = he[b];
    he[b] = c ? atomicAdd(&bcur_e[b], c) : 0u;   // bucket range base -> cursor
  }
  for (int b = t; b < NBN_CAP; b += 256) {
    unsigned c = hn[b];
    hn[b] = c ? atomicAdd(&bcur_n[b], c) : 0u;
  }
  __syncthreads();

  for (int idx = t; idx < cnt; idx += 256) {
    unsigned e = (unsigned)edge_idx[base + idx];
    unsigned n = (unsigned)node_idx[base + idx];
    unsigned pe = atomicAdd(&he[e >> E_SHIFT], 1u);
    tmp_e[pe] = ((e & 63u) << 17) | n;
    unsigned pn = atomicAdd(&hn[n >> N_SHIFT], 1u);
    tmp_n[pn] = ((n & 127u) << 15) | e;
  }
}

__device__ __forceinline__ float4 alpha4(const float* __restrict__ ai,
                                         const float* __restrict__ aj,
                                         unsigned n, unsigned e) {
  float4 av = *(const float4*)&ai[(size_t)n * 4];
  float4 bv = *(const float4*)&aj[(size_t)e * 4];
  float v0 = av.x + bv.x, v1 = av.y + bv.y, v2 = av.z + bv.z, v3 = av.w + bv.w;
  v0 = v0 > 0.f ? v0 : 0.2f * v0;
  v1 = v1 > 0.f ? v1 : 0.2f * v1;
  v2 = v2 > 0.f ? v2 : 0.2f * v2;
  v3 = v3 > 0.f ? v3 : 0.2f * v3;
  return make_float4(expf(v0), expf(v1), expf(v2), expf(v3));
}

// pass C (nodes): per-bucket LDS counting sort. Emits noff/dinv, node-ordered
// edge ids + RAW alpha stream, and rden (LDS-accumulated alpha sums).
__global__ __launch_bounds__(256) void sort_node_exp(const unsigned* __restrict__ tmp,
                                                     const unsigned* __restrict__ bbase,
                                                     int N_,
                                                     const float* __restrict__ ai,
                                                     const float* __restrict__ aj,
                                                     float* __restrict__ ealpha_n,
                                                     int* __restrict__ neid,
                                                     unsigned* __restrict__ noff,
                                                     float* __restrict__ dinv,
                                                     float* __restrict__ rden) {
  __shared__ unsigned cur[128];
  __shared__ unsigned sbuf[NB_CAP];
  __shared__ __align__(16) float dsum[128][4];
  __shared__ unsigned wtot;
  int b = blockIdx.x, t = threadIdx.x;
  int n0 = b << N_SHIFT;
  unsigned base = bbase[b];
  int cnt = (int)(bbase[b + 1] - base);
  if (t < 128) cur[t] = 0;
  for (int i = t; i < 512; i += 256) ((float*)dsum)[i] = 0.f;
  __syncthreads();
  for (int idx = t; idx < cnt; idx += 256) {
    unsigned key = tmp[base + idx] >> 15;
    atomicAdd(&cur[key], 1u);
  }
  __syncthreads();
  {  // exclusive scan of 128 counts across waves 0..1
    unsigned c = (t < 128) ? cur[t] : 0u;
    unsigned incl = wave_incl_scan(c);
    if (t == 63) wtot = incl;
    __syncthreads();
    unsigned excl = incl - c + ((t >= 64 && t < 128) ? wtot : 0u);
    if (t < 128) {
      int n = n0 + t;
      if (n < N_) {
        noff[n] = base + excl;
        dinv[n] = c ? 1.f / (float)c : 0.f;
      }
      cur[t] = excl;
    }
  }
  __syncthreads();
  for (int idx = t; idx < cnt; idx += 256) {
    unsigned p = tmp[base + idx];
    unsigned key = p >> 15;
    unsigned pos = atomicAdd(&cur[key], 1u);
    if (pos < NB_CAP) {
      sbuf[pos] = p;
    } else {  // overflow fallback (statistically never): pos is final slot
      unsigned e = p & 0x7FFFu;
      float4 al = alpha4(ai, aj, n0 + key, e);
      atomicAdd(&dsum[key][0], al.x); atomicAdd(&dsum[key][1], al.y);
      atomicAdd(&dsum[key][2], al.z); atomicAdd(&dsum[key][3], al.w);
      *(float4*)&ealpha_n[(size_t)(base + pos) * 4] = al;
      neid[base + pos] = (int)e;
    }
  }
  __syncthreads();
  int lim = min(cnt, NB_CAP);
  for (int idx = t; idx < lim; idx += 256) {
    unsigned p = sbuf[idx];
    unsigned nl = p >> 15, e = p & 0x7FFFu;
    float4 al = alpha4(ai, aj, n0 + nl, e);
    atomicAdd(&dsum[nl][0], al.x); atomicAdd(&dsum[nl][1], al.y);
    atomicAdd(&dsum[nl][2], al.z); atomicAdd(&dsum[nl][3], al.w);
    *(float4*)&ealpha_n[(size_t)(base + idx) * 4] = al;
    neid[base + idx] = (int)e;
  }
  __syncthreads();
  if (t < 128) {
    int n = n0 + t;
    if (n < N_) {
      *(float4*)&rden[(size_t)n * 4] =
          make_float4(1.f / (dsum[t][0] + 1e-16f), 1.f / (dsum[t][1] + 1e-16f),
                      1.f / (dsum[t][2] + 1e-16f), 1.f / (dsum[t][3] + 1e-16f));
    }
  }
}

// pass C (edges): per-bucket LDS counting sort; emits eoff/binv + coalesced
// edge-ordered node ids + PRE-NORMALIZED alpha (ealpha * rden[n] * binv[e]).
__global__ __launch_bounds__(256) void sort_edge_exp(const unsigned* __restrict__ tmp,
                                                     const unsigned* __restrict__ bbase,
                                                     int M_,
                                                     const float* __restrict__ ai,
                                                     const float* __restrict__ aj,
                                                     const float* __restrict__ rden,
                                                     float* __restrict__ alpha_e,
                                                     int* __restrict__ enid,
                                                     unsigned* __restrict__ eoff,
                                                     float* __restrict__ binv) {
  __shared__ unsigned cur[64];
  __shared__ float binv_s[64];
  __shared__ unsigned sbuf[EB_CAP];
  int b = blockIdx.x, t = threadIdx.x;
  int e0 = b << E_SHIFT;
  unsigned base = bbase[b];
  int cnt = (int)(bbase[b + 1] - base);
  if (t < 64) cur[t] = 0;
  __syncthreads();
  for (int idx = t; idx < cnt; idx += 256) {
    unsigned key = tmp[base + idx] >> 17;
    atomicAdd(&cur[key], 1u);
  }
  __syncthreads();
  {  // local exclusive scan of 64 counts (wave 0 relevant)
    unsigned c = (t < 64) ? cur[t] : 0u;
    unsigned incl = wave_incl_scan(c);
    unsigned excl = incl - c;
    if (t < 64) {
      float bv = c ? 1.f / (float)c : 0.f;
      binv_s[t] = bv;
      int e = e0 + t;
      if (e < M_) {
        eoff[e] = base + excl;
        binv[e] = bv;
      }
      cur[t] = excl;  // becomes the placement cursor
    }
  }
  __syncthreads();
  for (int idx = t; idx < cnt; idx += 256) {
    unsigned p = tmp[base + idx];
    unsigned key = p >> 17;
    unsigned pos = atomicAdd(&cur[key], 1u);
    if (pos < EB_CAP) {
      sbuf[pos] = p;
    } else {  // overflow fallback (statistically never): pos is final slot
      unsigned n = p & 0x1FFFFu;
      float4 al = alpha4(ai, aj, n, e0 + key);
      float4 rd = *(const float4*)&rden[(size_t)n * 4];
      float bv = binv_s[key];
      *(float4*)&alpha_e[(size_t)(base + pos) * 4] =
          make_float4(al.x * rd.x * bv, al.y * rd.y * bv, al.z * rd.z * bv, al.w * rd.w * bv);
      enid[base + pos] = (int)n;
    }
  }
  __syncthreads();
  int lim = min(cnt, EB_CAP);
  for (int idx = t; idx < lim; idx += 256) {
    unsigned p = sbuf[idx];
    unsigned key = p >> 17, n = p & 0x1FFFFu;
    float4 al = alpha4(ai, aj, n, e0 + key);
    float4 rd = *(const float4*)&rden[(size_t)n * 4];
    float bv = binv_s[key];
    *(float4*)&alpha_e[(size_t)(base + idx) * 4] =
        make_float4(al.x * rd.x * bv, al.y * rd.y * bv, al.z * rd.z * bv, al.w * rd.w * bv);
    enid[base + idx] = (int)n;
  }
}

// WT[k*128+o] = W[o*128+k]   (one-time 64KB transpose)
__global__ __launch_bounds__(256) void wtrans(const float* __restrict__ W,
                                              float* __restrict__ WT) {
  int idx = blockIdx.x * 256 + threadIdx.x;
  if (idx >= 128 * 128) return;
  int k = idx >> 7, o = idx & 127;
  WT[idx] = W[o * 128 + k];
}

// C[r,o] = sum_k A[r,k] * WT[k,o]; A rows x 128, WT 128x128 (pre-transposed).
// A-tile row-major in LDS: staging coalesced & conflict-free; reads broadcast.
// Optional fused head-dot epilogue: aiout[r,h] = sum_f C[r,h*32+f]*att[h*64+f].
#define GM 64
__global__ __launch_bounds__(256) void gemm128t(const float* __restrict__ A,
                                                const float* __restrict__ WT,
                                                float* __restrict__ C, int rows,
                                                const float* __restrict__ att,
                                                float* __restrict__ aiout) {
  __shared__ __align__(16) float Ast[GM][132];  // row-major, pad 132
  const int tid = threadIdx.x;
  const int row0 = blockIdx.x * GM;

  for (int idx = tid; idx < GM * 32; idx += 256) {  // float4-granular staging
    int r = idx >> 5, kq = idx & 31;
    int gr = row0 + r;
    float4 v = (gr < rows) ? *(const float4*)&A[(size_t)gr * 128 + kq * 4]
                           : make_float4(0.f, 0.f, 0.f, 0.f);
    *(float4*)&Ast[r][kq * 4] = v;
  }
  __syncthreads();

  const int tr = tid >> 5, tc = tid & 31;
  const int r0 = tr * 8, c0 = tc * 4;
  float acc[8][4] = {{0.f}};

  for (int k = 0; k < 128; k += 4) {
    float4 b0 = *(const float4*)&WT[(k + 0) * 128 + c0];
    float4 b1 = *(const float4*)&WT[(k + 1) * 128 + c0];
    float4 b2 = *(const float4*)&WT[(k + 2) * 128 + c0];
    float4 b3 = *(const float4*)&WT[(k + 3) * 128 + c0];
#pragma unroll
    for (int i = 0; i < 8; ++i) {
      float4 a = *(const float4*)&Ast[r0 + i][k];  // broadcast read
      acc[i][0] += a.x * b0.x; acc[i][1] += a.x * b0.y; acc[i][2] += a.x * b0.z; acc[i][3] += a.x * b0.w;
      acc[i][0] += a.y * b1.x; acc[i][1] += a.y * b1.y; acc[i][2] += a.y * b1.z; acc[i][3] += a.y * b1.w;
      acc[i][0] += a.z * b2.x; acc[i][1] += a.z * b2.y; acc[i][2] += a.z * b2.z; acc[i][3] += a.z * b2.w;
      acc[i][0] += a.w * b3.x; acc[i][1] += a.w * b3.y; acc[i][2] += a.w * b3.z; acc[i][3] += a.w * b3.w;
    }
  }

#pragma unroll
  for (int i = 0; i < 8; ++i) {
    int gr = row0 + r0 + i;
    if (gr < rows)
      *(float4*)&C[(size_t)gr * 128 + c0] = make_float4(acc[i][0], acc[i][1], acc[i][2], acc[i][3]);
  }

  if (att) {  // fused ai head-dot: cols c0..c0+3 all in head h = tc>>3
    int h = tc >> 3;
    float4 w = *(const float4*)&att[h * 64 + (c0 & 31)];
#pragma unroll
    for (int i = 0; i < 8; ++i) {
      float p = acc[i][0] * w.x + acc[i][1] * w.y + acc[i][2] * w.z + acc[i][3] * w.w;
      p += __shfl_xor(p, 1);
      p += __shfl_xor(p, 2);
      p += __shfl_xor(p, 4);
      if ((tc & 7) == 0) {
        int gr = row0 + r0 + i;
        if (gr < rows) aiout[(size_t)gr * 4 + h] = p;
      }
    }
  }
}

// u[h,k] = sum_f att1[h*64+32+f] * W_he[(h*32+f)*128 + k]
__global__ __launch_bounds__(256) void make_u(const float* __restrict__ W_he,
                                              const float* __restrict__ att1,
                                              float* __restrict__ u) {
  int idx = blockIdx.x * 256 + threadIdx.x;
  if (idx >= 512) return;
  int h = idx >> 7, k = idx & 127;
  float s = 0.f;
#pragma unroll
  for (int f = 0; f < 32; ++f)
    s += att1[h * 64 + 32 + f] * W_he[(size_t)(h * 32 + f) * 128 + k];
  u[h * 128 + k] = s;
}

// aj[e,h] = hea[e,:] . u[h,:]
__global__ __launch_bounds__(256) void att_dot_full(const float* __restrict__ feat,
                                                    const float* __restrict__ u,
                                                    float* __restrict__ outv, int rows) {
  int idx = blockIdx.x * 256 + threadIdx.x;
  if (idx >= rows * 4) return;
  int v = idx >> 2, h = idx & 3;
  const float4* fp = (const float4*)(feat + (size_t)v * 128);
  const float4* up = (const float4*)(u + h * 128);
  float s = 0.f;
#pragma unroll
  for (int q = 0; q < 32; ++q) {
    float4 a = up[q], f = fp[q];
    s += a.x * f.x + a.y * f.y + a.z * f.z + a.w * f.w;
  }
  outv[idx] = s;
}

// out_e[e,:] = sum_i alpha_pre[i,h] * x1[node_i,:]   (alpha pre-normalized)
// 4 quarters x 32 lanes; lane loads float4 (full 512B row per quarter).
__global__ __launch_bounds__(128) void edge_aggregate1(const float* __restrict__ x1,
                                                       const float* __restrict__ alpha_e,
                                                       const int* __restrict__ enid,
                                                       const unsigned* __restrict__ eoff,
                                                       float* __restrict__ out_e) {
  __shared__ float red[4][128];
  const int e = blockIdx.x, t = threadIdx.x;
  const int q = t >> 5, l = t & 31, hh = l >> 3;
  const unsigned s = eoff[e], en = eoff[e + 1];
  float4 A0 = make_float4(0.f, 0.f, 0.f, 0.f), A1 = A0, A2 = A0, A3 = A0;
  unsigned j = s + q;
  for (; j + 12 < en; j += 16) {
    int n0 = enid[j], n1 = enid[j + 4], n2 = enid[j + 8], n3 = enid[j + 12];
    float w0 = alpha_e[(size_t)j * 4 + hh];
    float w1 = alpha_e[(size_t)(j + 4) * 4 + hh];
    float w2 = alpha_e[(size_t)(j + 8) * 4 + hh];
    float w3 = alpha_e[(size_t)(j + 12) * 4 + hh];
    float4 a0 = *(const float4*)&x1[(size_t)n0 * 128 + l * 4];
    float4 a1 = *(const float4*)&x1[(size_t)n1 * 128 + l * 4];
    float4 a2 = *(const float4*)&x1[(size_t)n2 * 128 + l * 4];
    float4 a3 = *(const float4*)&x1[(size_t)n3 * 128 + l * 4];
    A0.x += w0 * a0.x; A0.y += w0 * a0.y; A0.z += w0 * a0.z; A0.w += w0 * a0.w;
    A1.x += w1 * a1.x; A1.y += w1 * a1.y; A1.z += w1 * a1.z; A1.w += w1 * a1.w;
    A2.x += w2 * a2.x; A2.y += w2 * a2.y; A2.z += w2 * a2.z; A2.w += w2 * a2.w;
    A3.x += w3 * a3.x; A3.y += w3 * a3.y; A3.z += w3 * a3.z; A3.w += w3 * a3.w;
  }
  for (; j < en; j += 4) {
    int n = enid[j];
    float w = alpha_e[(size_t)j * 4 + hh];
    float4 a = *(const float4*)&x1[(size_t)n * 128 + l * 4];
    A0.x += w * a.x; A0.y += w * a.y; A0.z += w * a.z; A0.w += w * a.w;
  }
  float4 A = make_float4((A0.x + A1.x) + (A2.x + A3.x), (A0.y + A1.y) + (A2.y + A3.y),
                         (A0.z + A1.z) + (A2.z + A3.z), (A0.w + A1.w) + (A2.w + A3.w));
  *(float4*)&red[q][l * 4] = A;
  __syncthreads();
  out_e[(size_t)e * 128 + t] = red[0][t] + red[1][t] + red[2][t] + red[3][t];
}

// h[v,:] = elu(Dinv[v]*rden[v,h] * sum_j ealpha_n[j,h]*out_e[neid[j],:] + bias1)
__global__ __launch_bounds__(128) void node_aggregate1(const float* __restrict__ out_e,
                                                       const float* __restrict__ ealpha_n,
                                                       const float* __restrict__ rden,
                                                       const float* __restrict__ dinv,
                                                       const float* __restrict__ bias1,
                                                       const int* __restrict__ neid,
                                                       const unsigned* __restrict__ noff,
                                                       float* __restrict__ hout) {
  __shared__ float red[4][128];
  const int v = blockIdx.x, t = threadIdx.x;
  const int q = t >> 5, l = t & 31, hh = l >> 3;
  const unsigned s = noff[v], en = noff[v + 1];
  float4 A0 = make_float4(0.f, 0.f, 0.f, 0.f), A1 = A0;
  unsigned j = s + q;
  for (; j + 4 < en; j += 8) {
    int e0 = neid[j], e1 = neid[j + 4];
    float w0 = ealpha_n[(size_t)j * 4 + hh];
    float w1 = ealpha_n[(size_t)(j + 4) * 4 + hh];
    float4 a0 = *(const float4*)&out_e[(size_t)e0 * 128 + l * 4];
    float4 a1 = *(const float4*)&out_e[(size_t)e1 * 128 + l * 4];
    A0.x += w0 * a0.x; A0.y += w0 * a0.y; A0.z += w0 * a0.z; A0.w += w0 * a0.w;
    A1.x += w1 * a1.x; A1.y += w1 * a1.y; A1.z += w1 * a1.z; A1.w += w1 * a1.w;
  }
  for (; j < en; j += 4) {
    int e0 = neid[j];
    float w = ealpha_n[(size_t)j * 4 + hh];
    float4 a = *(const float4*)&out_e[(size_t)e0 * 128 + l * 4];
    A0.x += w * a.x; A0.y += w * a.y; A0.z += w * a.z; A0.w += w * a.w;
  }
  float4 A = make_float4(A0.x + A1.x, A0.y + A1.y, A0.z + A1.z, A0.w + A1.w);
  *(float4*)&red[q][l * 4] = A;
  __syncthreads();
  float rd = dinv[v] * rden[(size_t)v * 4 + (t >> 5)];
  float val = rd * (red[0][t] + red[1][t] + red[2][t] + red[3][t]) + bias1[t];
  hout[(size_t)v * 128 + t] = val > 0.f ? val : expm1f(val);
}

// oe[e,:] = Binv[e] * sum_i h[node_i,:]
__global__ __launch_bounds__(128) void edge_aggregate2(const float* __restrict__ hfeat,
                                                       const float* __restrict__ binv,
                                                       const int* __restrict__ enid,
                                                       const unsigned* __restrict__ eoff,
                                                       float* __restrict__ oe) {
  __shared__ float red[4][128];
  const int e = blockIdx.x, t = threadIdx.x;
  const int q = t >> 5, l = t & 31;
  const unsigned s = eoff[e], en = eoff[e + 1];
  float4 A0 = make_float4(0.f, 0.f, 0.f, 0.f), A1 = A0, A2 = A0, A3 = A0;
  unsigned j = s + q;
  for (; j + 12 < en; j += 16) {
    int n0 = enid[j], n1 = enid[j + 4], n2 = enid[j + 8], n3 = enid[j + 12];
    float4 a0 = *(const float4*)&hfeat[(size_t)n0 * 128 + l * 4];
    float4 a1 = *(const float4*)&hfeat[(size_t)n1 * 128 + l * 4];
    float4 a2 = *(const float4*)&hfeat[(size_t)n2 * 128 + l * 4];
    float4 a3 = *(const float4*)&hfeat[(size_t)n3 * 128 + l * 4];
    A0.x += a0.x; A0.y += a0.y; A0.z += a0.z; A0.w += a0.w;
    A1.x += a1.x; A1.y += a1.y; A1.z += a1.z; A1.w += a1.w;
    A2.x += a2.x; A2.y += a2.y; A2.z += a2.z; A2.w += a2.w;
    A3.x += a3.x; A3.y += a3.y; A3.z += a3.z; A3.w += a3.w;
  }
  for (; j < en; j += 4) {
    int n = enid[j];
    float4 a = *(const float4*)&hfeat[(size_t)n * 128 + l * 4];
    A0.x += a.x; A0.y += a.y; A0.z += a.z; A0.w += a.w;
  }
  float4 A = make_float4((A0.x + A1.x) + (A2.x + A3.x), (A0.y + A1.y) + (A2.y + A3.y),
                         (A0.z + A1.z) + (A2.z + A3.z), (A0.w + A1.w) + (A2.w + A3.w));
  *(float4*)&red[q][l * 4] = A;
  __syncthreads();
  oe[(size_t)e * 128 + t] = binv[e] * (red[0][t] + red[1][t] + red[2][t] + red[3][t]);
}

// out[v,:] = Dinv[v] * sum_j oe2[neid[j],:] + bias2
__global__ __launch_bounds__(128) void node_aggregate2(const float* __restrict__ oe2,
                                                       const float* __restrict__ dinv,
                                                       const float* __restrict__ bias2,
                                                       const int* __restrict__ neid,
                                                       const unsigned* __restrict__ noff,
                                                       float* __restrict__ out) {
  __shared__ float red[4][128];
  const int v = blockIdx.x, t = threadIdx.x;
  const int q = t >> 5, l = t & 31;
  const unsigned s = noff[v], en = noff[v + 1];
  float4 A0 = make_float4(0.f, 0.f, 0.f, 0.f), A1 = A0;
  unsigned j = s + q;
  for (; j + 4 < en; j += 8) {
    int e0 = neid[j], e1 = neid[j + 4];
    float4 a0 = *(const float4*)&oe2[(size_t)e0 * 128 + l * 4];
    float4 a1 = *(const float4*)&oe2[(size_t)e1 * 128 + l * 4];
    A0.x += a0.x; A0.y += a0.y; A0.z += a0.z; A0.w += a0.w;
    A1.x += a1.x; A1.y += a1.y; A1.z += a1.z; A1.w += a1.w;
  }
  for (; j < en; j += 4) {
    int e0 = neid[j];
    float4 a = *(const float4*)&oe2[(size_t)e0 * 128 + l * 4];
    A0.x += a.x; A0.y += a.y; A0.z += a.z; A0.w += a.w;
  }
  float4 A = make_float4(A0.x + A1.x, A0.y + A1.y, A0.z + A1.z, A0.w + A1.w);
  *(float4*)&red[q][l * 4] = A;
  __syncthreads();
  out[(size_t)v * 128 + t] = dinv[v] * (red[0][t] + red[1][t] + red[2][t] + red[3][t]) + bias2[t];
}

extern "C" void kernel_launch(void* const* d_in, const int* in_sizes, int n_in,
                              void* d_out, int out_size, void* d_ws, size_t ws_size,
                              hipStream_t stream) {
  (void)n_in; (void)out_size; (void)ws_size;
  const float* x      = (const float*)d_in[0];
  const float* hea    = (const float*)d_in[1];
  const float* lin1W  = (const float*)d_in[2];
  const float* helinW = (const float*)d_in[3];
  const float* att1   = (const float*)d_in[4];
  const float* bias1  = (const float*)d_in[5];
  const float* lin2W  = (const float*)d_in[6];
  const float* bias2  = (const float*)d_in[7];
  const int* node_idx = (const int*)d_in[8];
  const int* edge_idx = (const int*)d_in[9];
  float* out = (float*)d_out;

  const int N   = in_sizes[0] / 128;
  const int M   = in_sizes[1] / 128;
  const int NNZ = in_sizes[8];
  const int NBE = (M + 63) >> E_SHIFT;
  const int NBN = (N + 127) >> N_SHIFT;

  char* base = (char*)d_ws;
  size_t off = 0;
  auto alloc = [&](size_t bytes) -> char* {
    char* p = base + off;
    off = (off + bytes + 255) & ~(size_t)255;
    return p;
  };
  float* x1    = (float*)alloc((size_t)N * 128 * 4);  // x1; later oe2 (M rows)
  float* hbuf  = (float*)alloc((size_t)N * 128 * 4);  // h
  float* heoe  = (float*)alloc((size_t)M * 128 * 4);  // out_e -> oe_pre
  float* ai    = (float*)alloc((size_t)N * 4 * 4);
  float* aj    = (float*)alloc((size_t)M * 4 * 4);
  float* u     = (float*)alloc(512 * 4);
  float* WT1   = (float*)alloc(128 * 128 * 4);
  float* WT2   = (float*)alloc(128 * 128 * 4);
  float* dinv  = (float*)alloc((size_t)N * 4);
  float* binv  = (float*)alloc((size_t)M * 4);
  float* rden  = (float*)alloc((size_t)N * 4 * 4);
  char* zstart = base + off;                           // ---- zeroed region ----
  unsigned* bcnt_e = (unsigned*)alloc((size_t)NBE * 4);
  unsigned* bcnt_n = (unsigned*)alloc((size_t)NBN * 4);
  size_t zbytes = (size_t)((base + off) - zstart);     // ---- end zero region ----
  float* alpha_e  = (float*)alloc((size_t)NNZ * 4 * 4);
  float* ealpha_n = (float*)alloc((size_t)NNZ * 4 * 4);
  unsigned* tmp_e = (unsigned*)alloc((size_t)NNZ * 4);
  unsigned* tmp_n = (unsigned*)alloc((size_t)NNZ * 4);
  unsigned* noff  = (unsigned*)alloc((size_t)(N + 1) * 4);
  unsigned* eoff  = (unsigned*)alloc((size_t)(M + 1) * 4);
  unsigned* bbase_e = (unsigned*)alloc((size_t)(NBE + 1) * 4);
  unsigned* bbase_n = (unsigned*)alloc((size_t)(NBN + 1) * 4);
  unsigned* bcur_e = (unsigned*)alloc((size_t)NBE * 4);
  unsigned* bcur_n = (unsigned*)alloc((size_t)NBN * 4);
  int* enid       = (int*)alloc((size_t)NNZ * 4);
  int* neid       = (int*)alloc((size_t)NNZ * 4);

  hipMemsetAsync(zstart, 0, zbytes, stream);

  const int g_pchunk = (NNZ + PCHUNK - 1) / PCHUNK;
  bucket_count<<<g_pchunk, 256, 0, stream>>>(node_idx, edge_idx, bcnt_e, bcnt_n, NNZ);
  bucket_scan<<<1, 1024, 0, stream>>>(bcnt_e, bcnt_n, bbase_e, bcur_e, bbase_n, bcur_n,
                                      eoff, noff, NBE, NBN, M, N, NNZ);
  partition2<<<g_pchunk, 256, 0, stream>>>(node_idx, edge_idx, bcur_e, bcur_n,
                                           tmp_e, tmp_n, NNZ);

  wtrans<<<64, 256, 0, stream>>>(lin1W, WT1);
  wtrans<<<64, 256, 0, stream>>>(lin2W, WT2);
  gemm128t<<<(N + GM - 1) / GM, 256, 0, stream>>>(x, WT1, x1, N, att1, ai);
  make_u<<<2, 256, 0, stream>>>(helinW, att1, u);
  att_dot_full<<<(M * 4 + 255) / 256, 256, 0, stream>>>(hea, u, aj, M);

  sort_node_exp<<<NBN, 256, 0, stream>>>(tmp_n, bbase_n, N, ai, aj, ealpha_n, neid,
                                         noff, dinv, rden);
  sort_edge_exp<<<NBE, 256, 0, stream>>>(tmp_e, bbase_e, M, ai, aj, rden, alpha_e, enid,
                                         eoff, binv);

  edge_aggregate1<<<M, 128, 0, stream>>>(x1, alpha_e, enid, eoff, heoe);
  node_aggregate1<<<N, 128, 0, stream>>>(heoe, ealpha_n, rden, dinv, bias1, neid, noff, hbuf);

  edge_aggregate2<<<M, 128, 0, stream>>>(hbuf, binv, enid, eoff, heoe);
  gemm128t<<<(M + GM - 1) / GM, 256, 0, stream>>>(heoe, WT2, x1, M, nullptr, nullptr);
  node_aggregate2<<<N, 128, 0, stream>>>(x1, dinv, bias2, neid, noff, out);
}

// Round 13
// 467.698 us; speedup vs baseline: 1.0656x; 1.0449x over previous
//
#include <hip/hip_runtime.h>
#include <cstdint>

// ---------------------------------------------------------------------------
// HCHA (hypergraph conv with attention), f32.
// N=100000 nodes, M=20000 hyperedges, NNZ=1e6, C=128, HEADS=4, FH=32.
// Round-9 configuration (best measured, 472 us): two-histogram CSR build,
// simple per-bucket sorts, separate streaming node_denom pass (measured
// faster than LDS-atomic rden fusion), pre-normalized edge alpha,
// float4-gather aggregates (4 quarters x 32 lanes, pinned at the
// ~3.4-3.5 TB/s random-gather L2-fill ceiling).
// GEMM: A-tile row-major in LDS, W^T pre-transposed, ai head-dot fused.
// Packing: e < 2^15 (M=20000), n < 2^17 (N=1e5).
// ---------------------------------------------------------------------------

#define E_SHIFT 6
#define N_SHIFT 7
#define EB_CAP 4096
#define NB_CAP 2048
#define PCHUNK 4096
#define NBE_CAP 320   // >= ceil(M/64)  = 313
#define NBN_CAP 800   // >= ceil(N/128) = 782

__device__ __forceinline__ unsigned wave_incl_scan(unsigned x) {
#pragma unroll
  for (int s = 1; s < 64; s <<= 1) {
    unsigned t = __shfl_up(x, s, 64);
    if ((int)(threadIdx.x & 63) >= s) x += t;
  }
  return x;
}

// pass A: per-block LDS bucket histogram -> one global atomicAdd per
// (block,bucket). No per-id atomics.
__global__ __launch_bounds__(256) void bucket_count(const int* __restrict__ node_idx,
                                                    const int* __restrict__ edge_idx,
                                                    unsigned* __restrict__ bcnt_e,
                                                    unsigned* __restrict__ bcnt_n, int nnz) {
  __shared__ unsigned he[NBE_CAP];
  __shared__ unsigned hn[NBN_CAP];
  const int t = threadIdx.x;
  const int base = blockIdx.x * PCHUNK;
  const int cnt = min(PCHUNK, nnz - base);
  for (int b = t; b < NBE_CAP; b += 256) he[b] = 0;
  for (int b = t; b < NBN_CAP; b += 256) hn[b] = 0;
  __syncthreads();
  for (int idx = t; idx < cnt; idx += 256) {
    unsigned e = (unsigned)edge_idx[base + idx];
    unsigned n = (unsigned)node_idx[base + idx];
    atomicAdd(&he[e >> E_SHIFT], 1u);
    atomicAdd(&hn[n >> N_SHIFT], 1u);
  }
  __syncthreads();
  for (int b = t; b < NBE_CAP; b += 256) if (he[b]) atomicAdd(&bcnt_e[b], he[b]);
  for (int b = t; b < NBN_CAP; b += 256) if (hn[b]) atomicAdd(&bcnt_n[b], hn[b]);
}

// single block: exclusive-scan bucket totals -> bucket bases + cursors;
// also writes eoff[M]=noff[N]=NNZ.
__global__ __launch_bounds__(1024) void bucket_scan(const unsigned* __restrict__ bcnt_e,
                                                    const unsigned* __restrict__ bcnt_n,
                                                    unsigned* __restrict__ bbase_e,
                                                    unsigned* __restrict__ bcur_e,
                                                    unsigned* __restrict__ bbase_n,
                                                    unsigned* __restrict__ bcur_n,
                                                    unsigned* __restrict__ eoff,
                                                    unsigned* __restrict__ noff,
                                                    int nbe, int nbn, int M_, int N_, int nnz) {
  __shared__ unsigned wsum[16];
  const int i = threadIdx.x;
  const int lane = i & 63, wid = i >> 6;
  {
    unsigned v = (i < nbe) ? bcnt_e[i] : 0u;
    unsigned incl = wave_incl_scan(v);
    if (lane == 63) wsum[wid] = incl;
    __syncthreads();
    unsigned add = 0;
    for (int w = 0; w < wid; ++w) add += wsum[w];
    unsigned excl = add + incl - v;
    if (i <= nbe) bbase_e[i] = excl;
    if (i < nbe) bcur_e[i] = excl;
    __syncthreads();
  }
  {
    unsigned v = (i < nbn) ? bcnt_n[i] : 0u;
    unsigned incl = wave_incl_scan(v);
    if (lane == 63) wsum[wid] = incl;
    __syncthreads();
    unsigned add = 0;
    for (int w = 0; w < wid; ++w) add += wsum[w];
    unsigned excl = add + incl - v;
    if (i <= nbn) bbase_n[i] = excl;
    if (i < nbn) bcur_n[i] = excl;
  }
  if (i == 0) { eoff[M_] = (unsigned)nnz; noff[N_] = (unsigned)nnz; }
}

// pass B: block-local multi-split. LDS histogram -> one global atomic per
// (block,bucket) to reserve ranges -> LDS-cursor scatter of u32 payloads.
__global__ __launch_bounds__(256) void partition2(const int* __restrict__ node_idx,
                                                  const int* __restrict__ edge_idx,
                                                  unsigned* __restrict__ bcur_e,
                                                  unsigned* __restrict__ bcur_n,
                                                  unsigned* __restrict__ tmp_e,
                                                  unsigned* __restrict__ tmp_n, int nnz) {
  __shared__ unsigned he[NBE_CAP];
  __shared__ unsigned hn[NBN_CAP];
  const int t = threadIdx.x;
  const int base = blockIdx.x * PCHUNK;
  const int cnt = min(PCHUNK, nnz - base);

  for (int b = t; b < NBE_CAP; b += 256) he[b] = 0;
  for (int b = t; b < NBN_CAP; b += 256) hn[b] = 0;
  __syncthreads();

  for (int idx = t; idx < cnt; idx += 256) {
    unsigned e = (unsigned)edge_idx[base + idx];
    unsigned n = (unsigned)node_idx[base + idx];
    atomicAdd(&he[e >> E_SHIFT], 1u);
    atomicAdd(&hn[n >> N_SHIFT], 1u);
  }
  __syncthreads();

  for (int b = t; b < NBE_CAP; b += 256) {
    unsigned c = he[b];
    he[b] = c ? atomicAdd(&bcur_e[b], c) : 0u;   // bucket range base -> cursor
  }
  for (int b = t; b < NBN_CAP; b += 256) {
    unsigned c = hn[b];
    hn[b] = c ? atomicAdd(&bcur_n[b], c) : 0u;
  }
  __syncthreads();

  for (int idx = t; idx < cnt; idx += 256) {
    unsigned e = (unsigned)edge_idx[base + idx];
    unsigned n = (unsigned)node_idx[base + idx];
    unsigned pe = atomicAdd(&he[e >> E_SHIFT], 1u);
    tmp_e[pe] = ((e & 63u) << 17) | n;
    unsigned pn = atomicAdd(&hn[n >> N_SHIFT], 1u);
    tmp_n[pn] = ((n & 127u) << 15) | e;
  }
}

__device__ __forceinline__ float4 alpha4(const float* __restrict__ ai,
                                         const float* __restrict__ aj,
                                         unsigned n, unsigned e) {
  float4 av = *(const float4*)&ai[(size_t)n * 4];
  float4 bv = *(const float4*)&aj[(size_t)e * 4];
  float v0 = av.x + bv.x, v1 = av.y + bv.y, v2 = av.z + bv.z, v3 = av.w + bv.w;
  v0 = v0 > 0.f ? v0 : 0.2f * v0;
  v1 = v1 > 0.f ? v1 : 0.2f * v1;
  v2 = v2 > 0.f ? v2 : 0.2f * v2;
  v3 = v3 > 0.f ? v3 : 0.2f * v3;
  return make_float4(expf(v0), expf(v1), expf(v2), expf(v3));
}

// pass C (nodes): per-bucket sort; emits noff/dinv + node-ordered edge ids
// and RAW alpha stream (rden is derived from this afterwards).
__global__ __launch_bounds__(256) void sort_node_exp(const unsigned* __restrict__ tmp,
                                                     const unsigned* __restrict__ bbase,
                                                     int N_,
                                                     const float* __restrict__ ai,
                                                     const float* __restrict__ aj,
                                                     float* __restrict__ ealpha_n,
                                                     int* __restrict__ neid,
                                                     unsigned* __restrict__ noff,
                                                     float* __restrict__ dinv) {
  __shared__ unsigned cur[128];
  __shared__ unsigned sbuf[NB_CAP];
  __shared__ unsigned wtot;
  int b = blockIdx.x, t = threadIdx.x;
  int n0 = b << N_SHIFT;
  unsigned base = bbase[b];
  int cnt = (int)(bbase[b + 1] - base);
  if (t < 128) cur[t] = 0;
  __syncthreads();
  for (int idx = t; idx < cnt; idx += 256) {
    unsigned key = tmp[base + idx] >> 15;
    atomicAdd(&cur[key], 1u);
  }
  __syncthreads();
  {  // exclusive scan of 128 counts across waves 0..1
    unsigned c = (t < 128) ? cur[t] : 0u;
    unsigned incl = wave_incl_scan(c);
    if (t == 63) wtot = incl;
    __syncthreads();
    unsigned excl = incl - c + ((t >= 64 && t < 128) ? wtot : 0u);
    if (t < 128) {
      int n = n0 + t;
      if (n < N_) {
        noff[n] = base + excl;
        dinv[n] = c ? 1.f / (float)c : 0.f;
      }
      cur[t] = excl;
    }
  }
  __syncthreads();
  for (int idx = t; idx < cnt; idx += 256) {
    unsigned p = tmp[base + idx];
    unsigned key = p >> 15;
    unsigned pos = atomicAdd(&cur[key], 1u);
    if (pos < NB_CAP) {
      sbuf[pos] = p;
    } else {
      unsigned e = p & 0x7FFFu;
      *(float4*)&ealpha_n[(size_t)(base + pos) * 4] = alpha4(ai, aj, n0 + key, e);
      neid[base + pos] = (int)e;
    }
  }
  __syncthreads();
  int lim = min(cnt, NB_CAP);
  for (int idx = t; idx < lim; idx += 256) {
    unsigned p = sbuf[idx];
    unsigned key = p >> 15, e = p & 0x7FFFu;
    *(float4*)&ealpha_n[(size_t)(base + idx) * 4] = alpha4(ai, aj, n0 + key, e);
    neid[base + idx] = (int)e;
  }
}

// rden[v,h] = 1/(sum_{j in node range} ealpha_n[j,h] + 1e-16), sequential read
__global__ __launch_bounds__(256) void node_denom2(const unsigned* __restrict__ noff,
                                                   const float* __restrict__ ealpha_n,
                                                   float* __restrict__ rden, int N) {
  int v = blockIdx.x * 256 + threadIdx.x;
  if (v >= N) return;
  unsigned s = noff[v], en = noff[v + 1];
  float x = 0.f, y = 0.f, z = 0.f, w = 0.f;
  for (unsigned j = s; j < en; ++j) {
    float4 a = *(const float4*)&ealpha_n[(size_t)j * 4];
    x += a.x; y += a.y; z += a.z; w += a.w;
  }
  *(float4*)&rden[(size_t)v * 4] = make_float4(1.f / (x + 1e-16f), 1.f / (y + 1e-16f),
                                               1.f / (z + 1e-16f), 1.f / (w + 1e-16f));
}

// pass C (edges): per-bucket LDS counting sort; emits eoff/binv + coalesced
// edge-ordered node ids + PRE-NORMALIZED alpha (ealpha * rden[n] * binv[e]).
__global__ __launch_bounds__(256) void sort_edge_exp(const unsigned* __restrict__ tmp,
                                                     const unsigned* __restrict__ bbase,
                                                     int M_,
                                                     const float* __restrict__ ai,
                                                     const float* __restrict__ aj,
                                                     const float* __restrict__ rden,
                                                     float* __restrict__ alpha_e,
                                                     int* __restrict__ enid,
                                                     unsigned* __restrict__ eoff,
                                                     float* __restrict__ binv) {
  __shared__ unsigned cur[64];
  __shared__ float binv_s[64];
  __shared__ unsigned sbuf[EB_CAP];
  int b = blockIdx.x, t = threadIdx.x;
  int e0 = b << E_SHIFT;
  unsigned base = bbase[b];
  int cnt = (int)(bbase[b + 1] - base);
  if (t < 64) cur[t] = 0;
  __syncthreads();
  for (int idx = t; idx < cnt; idx += 256) {
    unsigned key = tmp[base + idx] >> 17;
    atomicAdd(&cur[key], 1u);
  }
  __syncthreads();
  {  // local exclusive scan of 64 counts (wave 0 relevant)
    unsigned c = (t < 64) ? cur[t] : 0u;
    unsigned incl = wave_incl_scan(c);
    unsigned excl = incl - c;
    if (t < 64) {
      float bv = c ? 1.f / (float)c : 0.f;
      binv_s[t] = bv;
      int e = e0 + t;
      if (e < M_) {
        eoff[e] = base + excl;
        binv[e] = bv;
      }
      cur[t] = excl;  // becomes the placement cursor
    }
  }
  __syncthreads();
  for (int idx = t; idx < cnt; idx += 256) {
    unsigned p = tmp[base + idx];
    unsigned key = p >> 17;
    unsigned pos = atomicAdd(&cur[key], 1u);
    if (pos < EB_CAP) {
      sbuf[pos] = p;
    } else {  // overflow fallback (statistically never): pos is final slot
      unsigned n = p & 0x1FFFFu;
      float4 al = alpha4(ai, aj, n, e0 + key);
      float4 rd = *(const float4*)&rden[(size_t)n * 4];
      float bv = binv_s[key];
      *(float4*)&alpha_e[(size_t)(base + pos) * 4] =
          make_float4(al.x * rd.x * bv, al.y * rd.y * bv, al.z * rd.z * bv, al.w * rd.w * bv);
      enid[base + pos] = (int)n;
    }
  }
  __syncthreads();
  int lim = min(cnt, EB_CAP);
  for (int idx = t; idx < lim; idx += 256) {
    unsigned p = sbuf[idx];
    unsigned key = p >> 17, n = p & 0x1FFFFu;
    float4 al = alpha4(ai, aj, n, e0 + key);
    float4 rd = *(const float4*)&rden[(size_t)n * 4];
    float bv = binv_s[key];
    *(float4*)&alpha_e[(size_t)(base + idx) * 4] =
        make_float4(al.x * rd.x * bv, al.y * rd.y * bv, al.z * rd.z * bv, al.w * rd.w * bv);
    enid[base + idx] = (int)n;
  }
}

// WT[k*128+o] = W[o*128+k]   (one-time 64KB transpose)
__global__ __launch_bounds__(256) void wtrans(const float* __restrict__ W,
                                              float* __restrict__ WT) {
  int idx = blockIdx.x * 256 + threadIdx.x;
  if (idx >= 128 * 128) return;
  int k = idx >> 7, o = idx & 127;
  WT[idx] = W[o * 128 + k];
}

// C[r,o] = sum_k A[r,k] * WT[k,o]; A rows x 128, WT 128x128 (pre-transposed).
// A-tile row-major in LDS: staging coalesced & conflict-free; reads broadcast.
// Optional fused head-dot epilogue: aiout[r,h] = sum_f C[r,h*32+f]*att[h*64+f].
#define GM 64
__global__ __launch_bounds__(256) void gemm128t(const float* __restrict__ A,
                                                const float* __restrict__ WT,
                                                float* __restrict__ C, int rows,
                                                const float* __restrict__ att,
                                                float* __restrict__ aiout) {
  __shared__ __align__(16) float Ast[GM][132];  // row-major, pad 132
  const int tid = threadIdx.x;
  const int row0 = blockIdx.x * GM;

  for (int idx = tid; idx < GM * 32; idx += 256) {  // float4-granular staging
    int r = idx >> 5, kq = idx & 31;
    int gr = row0 + r;
    float4 v = (gr < rows) ? *(const float4*)&A[(size_t)gr * 128 + kq * 4]
                           : make_float4(0.f, 0.f, 0.f, 0.f);
    *(float4*)&Ast[r][kq * 4] = v;
  }
  __syncthreads();

  const int tr = tid >> 5, tc = tid & 31;
  const int r0 = tr * 8, c0 = tc * 4;
  float acc[8][4] = {{0.f}};

  for (int k = 0; k < 128; k += 4) {
    float4 b0 = *(const float4*)&WT[(k + 0) * 128 + c0];
    float4 b1 = *(const float4*)&WT[(k + 1) * 128 + c0];
    float4 b2 = *(const float4*)&WT[(k + 2) * 128 + c0];
    float4 b3 = *(const float4*)&WT[(k + 3) * 128 + c0];
#pragma unroll
    for (int i = 0; i < 8; ++i) {
      float4 a = *(const float4*)&Ast[r0 + i][k];  // broadcast read
      acc[i][0] += a.x * b0.x; acc[i][1] += a.x * b0.y; acc[i][2] += a.x * b0.z; acc[i][3] += a.x * b0.w;
      acc[i][0] += a.y * b1.x; acc[i][1] += a.y * b1.y; acc[i][2] += a.y * b1.z; acc[i][3] += a.y * b1.w;
      acc[i][0] += a.z * b2.x; acc[i][1] += a.z * b2.y; acc[i][2] += a.z * b2.z; acc[i][3] += a.z * b2.w;
      acc[i][0] += a.w * b3.x; acc[i][1] += a.w * b3.y; acc[i][2] += a.w * b3.z; acc[i][3] += a.w * b3.w;
    }
  }

#pragma unroll
  for (int i = 0; i < 8; ++i) {
    int gr = row0 + r0 + i;
    if (gr < rows)
      *(float4*)&C[(size_t)gr * 128 + c0] = make_float4(acc[i][0], acc[i][1], acc[i][2], acc[i][3]);
  }

  if (att) {  // fused ai head-dot: cols c0..c0+3 all in head h = tc>>3
    int h = tc >> 3;
    float4 w = *(const float4*)&att[h * 64 + (c0 & 31)];
#pragma unroll
    for (int i = 0; i < 8; ++i) {
      float p = acc[i][0] * w.x + acc[i][1] * w.y + acc[i][2] * w.z + acc[i][3] * w.w;
      p += __shfl_xor(p, 1);
      p += __shfl_xor(p, 2);
      p += __shfl_xor(p, 4);
      if ((tc & 7) == 0) {
        int gr = row0 + r0 + i;
        if (gr < rows) aiout[(size_t)gr * 4 + h] = p;
      }
    }
  }
}

// u[h,k] = sum_f att1[h*64+32+f] * W_he[(h*32+f)*128 + k]
__global__ __launch_bounds__(256) void make_u(const float* __restrict__ W_he,
                                              const float* __restrict__ att1,
                                              float* __restrict__ u) {
  int idx = blockIdx.x * 256 + threadIdx.x;
  if (idx >= 512) return;
  int h = idx >> 7, k = idx & 127;
  float s = 0.f;
#pragma unroll
  for (int f = 0; f < 32; ++f)
    s += att1[h * 64 + 32 + f] * W_he[(size_t)(h * 32 + f) * 128 + k];
  u[h * 128 + k] = s;
}

// aj[e,h] = hea[e,:] . u[h,:]
__global__ __launch_bounds__(256) void att_dot_full(const float* __restrict__ feat,
                                                    const float* __restrict__ u,
                                                    float* __restrict__ outv, int rows) {
  int idx = blockIdx.x * 256 + threadIdx.x;
  if (idx >= rows * 4) return;
  int v = idx >> 2, h = idx & 3;
  const float4* fp = (const float4*)(feat + (size_t)v * 128);
  const float4* up = (const float4*)(u + h * 128);
  float s = 0.f;
#pragma unroll
  for (int q = 0; q < 32; ++q) {
    float4 a = up[q], f = fp[q];
    s += a.x * f.x + a.y * f.y + a.z * f.z + a.w * f.w;
  }
  outv[idx] = s;
}

// out_e[e,:] = sum_i alpha_pre[i,h] * x1[node_i,:]   (alpha pre-normalized)
// 4 quarters x 32 lanes; lane loads float4 (full 512B row per quarter).
__global__ __launch_bounds__(128) void edge_aggregate1(const float* __restrict__ x1,
                                                       const float* __restrict__ alpha_e,
                                                       const int* __restrict__ enid,
                                                       const unsigned* __restrict__ eoff,
                                                       float* __restrict__ out_e) {
  __shared__ float red[4][128];
  const int e = blockIdx.x, t = threadIdx.x;
  const int q = t >> 5, l = t & 31, hh = l >> 3;
  const unsigned s = eoff[e], en = eoff[e + 1];
  float4 A0 = make_float4(0.f, 0.f, 0.f, 0.f), A1 = A0, A2 = A0, A3 = A0;
  unsigned j = s + q;
  for (; j + 12 < en; j += 16) {
    int n0 = enid[j], n1 = enid[j + 4], n2 = enid[j + 8], n3 = enid[j + 12];
    float w0 = alpha_e[(size_t)j * 4 + hh];
    float w1 = alpha_e[(size_t)(j + 4) * 4 + hh];
    float w2 = alpha_e[(size_t)(j + 8) * 4 + hh];
    float w3 = alpha_e[(size_t)(j + 12) * 4 + hh];
    float4 a0 = *(const float4*)&x1[(size_t)n0 * 128 + l * 4];
    float4 a1 = *(const float4*)&x1[(size_t)n1 * 128 + l * 4];
    float4 a2 = *(const float4*)&x1[(size_t)n2 * 128 + l * 4];
    float4 a3 = *(const float4*)&x1[(size_t)n3 * 128 + l * 4];
    A0.x += w0 * a0.x; A0.y += w0 * a0.y; A0.z += w0 * a0.z; A0.w += w0 * a0.w;
    A1.x += w1 * a1.x; A1.y += w1 * a1.y; A1.z += w1 * a1.z; A1.w += w1 * a1.w;
    A2.x += w2 * a2.x; A2.y += w2 * a2.y; A2.z += w2 * a2.z; A2.w += w2 * a2.w;
    A3.x += w3 * a3.x; A3.y += w3 * a3.y; A3.z += w3 * a3.z; A3.w += w3 * a3.w;
  }
  for (; j < en; j += 4) {
    int n = enid[j];
    float w = alpha_e[(size_t)j * 4 + hh];
    float4 a = *(const float4*)&x1[(size_t)n * 128 + l * 4];
    A0.x += w * a.x; A0.y += w * a.y; A0.z += w * a.z; A0.w += w * a.w;
  }
  float4 A = make_float4((A0.x + A1.x) + (A2.x + A3.x), (A0.y + A1.y) + (A2.y + A3.y),
                         (A0.z + A1.z) + (A2.z + A3.z), (A0.w + A1.w) + (A2.w + A3.w));
  *(float4*)&red[q][l * 4] = A;
  __syncthreads();
  out_e[(size_t)e * 128 + t] = red[0][t] + red[1][t] + red[2][t] + red[3][t];
}

// h[v,:] = elu(Dinv[v]*rden[v,h] * sum_j ealpha_n[j,h]*out_e[neid[j],:] + bias1)
__global__ __launch_bounds__(128) void node_aggregate1(const float* __restrict__ out_e,
                                                       const float* __restrict__ ealpha_n,
                                                       const float* __restrict__ rden,
                                                       const float* __restrict__ dinv,
                                                       const float* __restrict__ bias1,
                                                       const int* __restrict__ neid,
                                                       const unsigned* __restrict__ noff,
                                                       float* __restrict__ hout) {
  __shared__ float red[4][128];
  const int v = blockIdx.x, t = threadIdx.x;
  const int q = t >> 5, l = t & 31, hh = l >> 3;
  const unsigned s = noff[v], en = noff[v + 1];
  float4 A0 = make_float4(0.f, 0.f, 0.f, 0.f), A1 = A0;
  unsigned j = s + q;
  for (; j + 4 < en; j += 8) {
    int e0 = neid[j], e1 = neid[j + 4];
    float w0 = ealpha_n[(size_t)j * 4 + hh];
    float w1 = ealpha_n[(size_t)(j + 4) * 4 + hh];
    float4 a0 = *(const float4*)&out_e[(size_t)e0 * 128 + l * 4];
    float4 a1 = *(const float4*)&out_e[(size_t)e1 * 128 + l * 4];
    A0.x += w0 * a0.x; A0.y += w0 * a0.y; A0.z += w0 * a0.z; A0.w += w0 * a0.w;
    A1.x += w1 * a1.x; A1.y += w1 * a1.y; A1.z += w1 * a1.z; A1.w += w1 * a1.w;
  }
  for (; j < en; j += 4) {
    int e0 = neid[j];
    float w = ealpha_n[(size_t)j * 4 + hh];
    float4 a = *(const float4*)&out_e[(size_t)e0 * 128 + l * 4];
    A0.x += w * a.x; A0.y += w * a.y; A0.z += w * a.z; A0.w += w * a.w;
  }
  float4 A = make_float4(A0.x + A1.x, A0.y + A1.y, A0.z + A1.z, A0.w + A1.w);
  *(float4*)&red[q][l * 4] = A;
  __syncthreads();
  float rd = dinv[v] * rden[(size_t)v * 4 + (t >> 5)];
  float val = rd * (red[0][t] + red[1][t] + red[2][t] + red[3][t]) + bias1[t];
  hout[(size_t)v * 128 + t] = val > 0.f ? val : expm1f(val);
}

// oe[e,:] = Binv[e] * sum_i h[node_i,:]
__global__ __launch_bounds__(128) void edge_aggregate2(const float* __restrict__ hfeat,
                                                       const float* __restrict__ binv,
                                                       const int* __restrict__ enid,
                                                       const unsigned* __restrict__ eoff,
                                                       float* __restrict__ oe) {
  __shared__ float red[4][128];
  const int e = blockIdx.x, t = threadIdx.x;
  const int q = t >> 5, l = t & 31;
  const unsigned s = eoff[e], en = eoff[e + 1];
  float4 A0 = make_float4(0.f, 0.f, 0.f, 0.f), A1 = A0, A2 = A0, A3 = A0;
  unsigned j = s + q;
  for (; j + 12 < en; j += 16) {
    int n0 = enid[j], n1 = enid[j + 4], n2 = enid[j + 8], n3 = enid[j + 12];
    float4 a0 = *(const float4*)&hfeat[(size_t)n0 * 128 + l * 4];
    float4 a1 = *(const float4*)&hfeat[(size_t)n1 * 128 + l * 4];
    float4 a2 = *(const float4*)&hfeat[(size_t)n2 * 128 + l * 4];
    float4 a3 = *(const float4*)&hfeat[(size_t)n3 * 128 + l * 4];
    A0.x += a0.x; A0.y += a0.y; A0.z += a0.z; A0.w += a0.w;
    A1.x += a1.x; A1.y += a1.y; A1.z += a1.z; A1.w += a1.w;
    A2.x += a2.x; A2.y += a2.y; A2.z += a2.z; A2.w += a2.w;
    A3.x += a3.x; A3.y += a3.y; A3.z += a3.z; A3.w += a3.w;
  }
  for (; j < en; j += 4) {
    int n = enid[j];
    float4 a = *(const float4*)&hfeat[(size_t)n * 128 + l * 4];
    A0.x += a.x; A0.y += a.y; A0.z += a.z; A0.w += a.w;
  }
  float4 A = make_float4((A0.x + A1.x) + (A2.x + A3.x), (A0.y + A1.y) + (A2.y + A3.y),
                         (A0.z + A1.z) + (A2.z + A3.z), (A0.w + A1.w) + (A2.w + A3.w));
  *(float4*)&red[q][l * 4] = A;
  __syncthreads();
  oe[(size_t)e * 128 + t] = binv[e] * (red[0][t] + red[1][t] + red[2][t] + red[3][t]);
}

// out[v,:] = Dinv[v] * sum_j oe2[neid[j],:] + bias2
__global__ __launch_bounds__(128) void node_aggregate2(const float* __restrict__ oe2,
                                                       const float* __restrict__ dinv,
                                                       const float* __restrict__ bias2,
                                                       const int* __restrict__ neid,
                                                       const unsigned* __restrict__ noff,
                                                       float* __restrict__ out) {
  __shared__ float red[4][128];
  const int v = blockIdx.x, t = threadIdx.x;
  const int q = t >> 5, l = t & 31;
  const unsigned s = noff[v], en = noff[v + 1];
  float4 A0 = make_float4(0.f, 0.f, 0.f, 0.f), A1 = A0;
  unsigned j = s + q;
  for (; j + 4 < en; j += 8) {
    int e0 = neid[j], e1 = neid[j + 4];
    float4 a0 = *(const float4*)&oe2[(size_t)e0 * 128 + l * 4];
    float4 a1 = *(const float4*)&oe2[(size_t)e1 * 128 + l * 4];
    A0.x += a0.x; A0.y += a0.y; A0.z += a0.z; A0.w += a0.w;
    A1.x += a1.x; A1.y += a1.y; A1.z += a1.z; A1.w += a1.w;
  }
  for (; j < en; j += 4) {
    int e0 = neid[j];
    float4 a = *(const float4*)&oe2[(size_t)e0 * 128 + l * 4];
    A0.x += a.x; A0.y += a.y; A0.z += a.z; A0.w += a.w;
  }
  float4 A = make_float4(A0.x + A1.x, A0.y + A1.y, A0.z + A1.z, A0.w + A1.w);
  *(float4*)&red[q][l * 4] = A;
  __syncthreads();
  out[(size_t)v * 128 + t] = dinv[v] * (red[0][t] + red[1][t] + red[2][t] + red[3][t]) + bias2[t];
}

extern "C" void kernel_launch(void* const* d_in, const int* in_sizes, int n_in,
                              void* d_out, int out_size, void* d_ws, size_t ws_size,
                              hipStream_t stream) {
  (void)n_in; (void)out_size; (void)ws_size;
  const float* x      = (const float*)d_in[0];
  const float* hea    = (const float*)d_in[1];
  const float* lin1W  = (const float*)d_in[2];
  const float* helinW = (const float*)d_in[3];
  const float* att1   = (const float*)d_in[4];
  const float* bias1  = (const float*)d_in[5];
  const float* lin2W  = (const float*)d_in[6];
  const float* bias2  = (const float*)d_in[7];
  const int* node_idx = (const int*)d_in[8];
  const int* edge_idx = (const int*)d_in[9];
  float* out = (float*)d_out;

  const int N   = in_sizes[0] / 128;
  const int M   = in_sizes[1] / 128;
  const int NNZ = in_sizes[8];
  const int NBE = (M + 63) >> E_SHIFT;
  const int NBN = (N + 127) >> N_SHIFT;

  char* base = (char*)d_ws;
  size_t off = 0;
  auto alloc = [&](size_t bytes) -> char* {
    char* p = base + off;
    off = (off + bytes + 255) & ~(size_t)255;
    return p;
  };
  float* x1    = (float*)alloc((size_t)N * 128 * 4);  // x1; later oe2 (M rows)
  float* hbuf  = (float*)alloc((size_t)N * 128 * 4);  // h
  float* heoe  = (float*)alloc((size_t)M * 128 * 4);  // out_e -> oe_pre
  float* ai    = (float*)alloc((size_t)N * 4 * 4);
  float* aj    = (float*)alloc((size_t)M * 4 * 4);
  float* u     = (float*)alloc(512 * 4);
  float* WT1   = (float*)alloc(128 * 128 * 4);
  float* WT2   = (float*)alloc(128 * 128 * 4);
  float* dinv  = (float*)alloc((size_t)N * 4);
  float* binv  = (float*)alloc((size_t)M * 4);
  float* rden  = (float*)alloc((size_t)N * 4 * 4);
  char* zstart = base + off;                           // ---- zeroed region ----
  unsigned* bcnt_e = (unsigned*)alloc((size_t)NBE * 4);
  unsigned* bcnt_n = (unsigned*)alloc((size_t)NBN * 4);
  size_t zbytes = (size_t)((base + off) - zstart);     // ---- end zero region ----
  float* alpha_e  = (float*)alloc((size_t)NNZ * 4 * 4);
  float* ealpha_n = (float*)alloc((size_t)NNZ * 4 * 4);
  unsigned* tmp_e = (unsigned*)alloc((size_t)NNZ * 4);
  unsigned* tmp_n = (unsigned*)alloc((size_t)NNZ * 4);
  unsigned* noff  = (unsigned*)alloc((size_t)(N + 1) * 4);
  unsigned* eoff  = (unsigned*)alloc((size_t)(M + 1) * 4);
  unsigned* bbase_e = (unsigned*)alloc((size_t)(NBE + 1) * 4);
  unsigned* bbase_n = (unsigned*)alloc((size_t)(NBN + 1) * 4);
  unsigned* bcur_e = (unsigned*)alloc((size_t)NBE * 4);
  unsigned* bcur_n = (unsigned*)alloc((size_t)NBN * 4);
  int* enid       = (int*)alloc((size_t)NNZ * 4);
  int* neid       = (int*)alloc((size_t)NNZ * 4);

  hipMemsetAsync(zstart, 0, zbytes, stream);

  const int g_pchunk = (NNZ + PCHUNK - 1) / PCHUNK;
  bucket_count<<<g_pchunk, 256, 0, stream>>>(node_idx, edge_idx, bcnt_e, bcnt_n, NNZ);
  bucket_scan<<<1, 1024, 0, stream>>>(bcnt_e, bcnt_n, bbase_e, bcur_e, bbase_n, bcur_n,
                                      eoff, noff, NBE, NBN, M, N, NNZ);
  partition2<<<g_pchunk, 256, 0, stream>>>(node_idx, edge_idx, bcur_e, bcur_n,
                                           tmp_e, tmp_n, NNZ);

  wtrans<<<64, 256, 0, stream>>>(lin1W, WT1);
  wtrans<<<64, 256, 0, stream>>>(lin2W, WT2);
  gemm128t<<<(N + GM - 1) / GM, 256, 0, stream>>>(x, WT1, x1, N, att1, ai);
  make_u<<<2, 256, 0, stream>>>(helinW, att1, u);
  att_dot_full<<<(M * 4 + 255) / 256, 256, 0, stream>>>(hea, u, aj, M);

  sort_node_exp<<<NBN, 256, 0, stream>>>(tmp_n, bbase_n, N, ai, aj, ealpha_n, neid,
                                         noff, dinv);
  node_denom2<<<(N + 255) / 256, 256, 0, stream>>>(noff, ealpha_n, rden, N);
  sort_edge_exp<<<NBE, 256, 0, stream>>>(tmp_e, bbase_e, M, ai, aj, rden, alpha_e, enid,
                                         eoff, binv);

  edge_aggregate1<<<M, 128, 0, stream>>>(x1, alpha_e, enid, eoff, heoe);
  node_aggregate1<<<N, 128, 0, stream>>>(heoe, ealpha_n, rden, dinv, bias1, neid, noff, hbuf);

  edge_aggregate2<<<M, 128, 0, stream>>>(hbuf, binv, enid, eoff, heoe);
  gemm128t<<<(M + GM - 1) / GM, 256, 0, stream>>>(heoe, WT2, x1, M, nullptr, nullptr);
  node_aggregate2<<<N, 128, 0, stream>>>(x1, dinv, bias2, neid, noff, out);
}